// Round 1
// baseline (981.064 us; speedup 1.0000x reference)
//
#include <hip/hip_runtime.h>
#include <hip/hip_bf16.h>

typedef unsigned short u16;
typedef __attribute__((ext_vector_type(4))) float f32x4;
typedef __attribute__((ext_vector_type(8))) short bf16x8;

#define B_ 2
#define S_ 2048
#define HID_ 2048
#define H_ 32
#define KVH_ 4
#define D_ 128
#define M_ 4096
#define NQ_ 4096
#define NKV_ 512

static __device__ __forceinline__ u16 f2b(float f) {
  union { float f; unsigned i; } x; x.f = f;
  return (u16)((x.i + 0x7fffu + ((x.i >> 16) & 1u)) >> 16);
}
static __device__ __forceinline__ float b2f(u16 u) {
  union { unsigned i; float f; } x; x.i = ((unsigned)u) << 16;
  return x.f;
}

// ---------------- fp32 -> bf16 elementwise ----------------
__global__ void k_cvt(const float* __restrict__ in, u16* __restrict__ out, int n4) {
  int i = blockIdx.x * blockDim.x + threadIdx.x;
  int stride = gridDim.x * blockDim.x;
  for (; i < n4; i += stride) {
    float4 v = reinterpret_cast<const float4*>(in)[i];
    ushort4 o;
    o.x = f2b(v.x); o.y = f2b(v.y); o.z = f2b(v.z); o.w = f2b(v.w);
    reinterpret_cast<ushort4*>(out)[i] = o;
  }
}

// ---------------- W fp32 [K][N] -> Wt bf16 [N][K] ----------------
__global__ __launch_bounds__(256) void k_transpose(const float* __restrict__ W,
                                                   u16* __restrict__ Wt, int K, int N) {
  __shared__ u16 t[64][72];
  int n0 = blockIdx.x * 64, k0 = blockIdx.y * 64;
  int tid = threadIdx.x;
  int r = tid >> 4;          // 0..15
  int c4 = (tid & 15) * 4;   // 0..60
#pragma unroll
  for (int i = 0; i < 4; i++) {
    int k = r + i * 16;
    float4 v = *reinterpret_cast<const float4*>(W + (size_t)(k0 + k) * N + n0 + c4);
    t[k][c4 + 0] = f2b(v.x); t[k][c4 + 1] = f2b(v.y);
    t[k][c4 + 2] = f2b(v.z); t[k][c4 + 3] = f2b(v.w);
  }
  __syncthreads();
#pragma unroll
  for (int i = 0; i < 4; i++) {
    int n = r + i * 16;
    ushort4 o;
    o.x = t[c4 + 0][n]; o.y = t[c4 + 1][n]; o.z = t[c4 + 2][n]; o.w = t[c4 + 3][n];
    *reinterpret_cast<ushort4*>(Wt + (size_t)(n0 + n) * K + k0 + c4) = o;
  }
}

// ---------------- shared 128x128 bf16 GEMM core (A [M][K], Bt [N][K]) ----------------
__device__ __forceinline__ void gemm_core(const u16* __restrict__ A, const u16* __restrict__ Bt,
                                          int K, int m0, int n0,
                                          u16* As, u16* Bs, f32x4 (&acc)[4][4]) {
  const int tid = threadIdx.x;
  const int lane = tid & 63;
  const int wid = tid >> 6;
  const int wr = wid >> 1, wc = wid & 1;
  const int lrow = lane & 15;
  const int lk8 = (lane >> 4) * 8;
  const f32x4 zz = {0.f, 0.f, 0.f, 0.f};
#pragma unroll
  for (int i = 0; i < 4; i++)
#pragma unroll
    for (int j = 0; j < 4; j++) acc[i][j] = zz;

  const int mrow = tid >> 3;      // 0..31
  const int kk = (tid & 7) * 8;   // 0..56

  for (int k0 = 0; k0 < K; k0 += 64) {
#pragma unroll
    for (int p = 0; p < 4; p++) {
      int m = mrow + p * 32;
      *reinterpret_cast<bf16x8*>(As + m * 72 + kk) =
          *reinterpret_cast<const bf16x8*>(A + (size_t)(m0 + m) * K + k0 + kk);
      *reinterpret_cast<bf16x8*>(Bs + m * 72 + kk) =
          *reinterpret_cast<const bf16x8*>(Bt + (size_t)(n0 + m) * K + k0 + kk);
    }
    __syncthreads();
#pragma unroll
    for (int kc = 0; kc < 2; kc++) {
      bf16x8 af[4], bfr[4];
#pragma unroll
      for (int i = 0; i < 4; i++)
        af[i] = *reinterpret_cast<const bf16x8*>(As + (wr * 64 + i * 16 + lrow) * 72 + kc * 32 + lk8);
#pragma unroll
      for (int j = 0; j < 4; j++)
        bfr[j] = *reinterpret_cast<const bf16x8*>(Bs + (wc * 64 + j * 16 + lrow) * 72 + kc * 32 + lk8);
#pragma unroll
      for (int i = 0; i < 4; i++)
#pragma unroll
        for (int j = 0; j < 4; j++)
          acc[i][j] = __builtin_amdgcn_mfma_f32_16x16x32_bf16(af[i], bfr[j], acc[i][j], 0, 0, 0);
    }
    __syncthreads();
  }
}

// ---------------- QKV projection ----------------
__global__ __launch_bounds__(256, 2) void k_gemm_qkv(const u16* __restrict__ hb,
    const u16* __restrict__ qwt, const u16* __restrict__ kwt, const u16* __restrict__ vwt,
    u16* __restrict__ qb, u16* __restrict__ kb, u16* __restrict__ vb) {
  __shared__ u16 As[128 * 72], Bs[128 * 72];
  int mt = blockIdx.x, nt = blockIdx.y;
  const u16* Bt; u16* dst; int head, nh;
  if (nt < 32)      { Bt = qwt; dst = qb; head = nt;      nh = H_;   }
  else if (nt < 36) { Bt = kwt; dst = kb; head = nt - 32; nh = KVH_; }
  else              { Bt = vwt; dst = vb; head = nt - 36; nh = KVH_; }
  f32x4 acc[4][4];
  gemm_core(hb, Bt, HID_, mt * 128, head * 128, As, Bs, acc);
  const int lane = threadIdx.x & 63;
  const int wid = threadIdx.x >> 6;
  const int wr = wid >> 1, wc = wid & 1;
  const int lr4 = (lane >> 4) * 4, lc = lane & 15;
#pragma unroll
  for (int i = 0; i < 4; i++)
#pragma unroll
    for (int j = 0; j < 4; j++)
#pragma unroll
      for (int r = 0; r < 4; r++) {
        int m = mt * 128 + wr * 64 + i * 16 + lr4 + r;
        int d = wc * 64 + j * 16 + lc;
        int b = m >> 11, s = m & (S_ - 1);
        dst[(((size_t)b * nh + head) * S_ + s) * D_ + d] = f2b(acc[i][j][r]);
      }
}

// ---------------- O projection ----------------
__global__ __launch_bounds__(256, 2) void k_gemm_o(const u16* __restrict__ ab,
    const u16* __restrict__ owt, float* __restrict__ out) {
  __shared__ u16 As[128 * 72], Bs[128 * 72];
  int mt = blockIdx.x, nt = blockIdx.y;
  f32x4 acc[4][4];
  gemm_core(ab, owt, NQ_, mt * 128, nt * 128, As, Bs, acc);
  const int lane = threadIdx.x & 63;
  const int wid = threadIdx.x >> 6;
  const int wr = wid >> 1, wc = wid & 1;
  const int lr4 = (lane >> 4) * 4, lc = lane & 15;
#pragma unroll
  for (int i = 0; i < 4; i++)
#pragma unroll
    for (int j = 0; j < 4; j++)
#pragma unroll
      for (int r = 0; r < 4; r++) {
        int m = mt * 128 + wr * 64 + i * 16 + lr4 + r;
        int n = nt * 128 + wc * 64 + j * 16 + lc;
        out[(size_t)m * HID_ + n] = acc[i][j][r];
      }
}

// ---------------- RMSNorm + RoPE (in place on q/k) ----------------
__global__ __launch_bounds__(256) void k_norm_rope(u16* __restrict__ qb, u16* __restrict__ kb,
    const float* __restrict__ cosp, const float* __restrict__ sinp,
    const float* __restrict__ qnw, const float* __restrict__ knw) {
  int row = blockIdx.x * 4 + (threadIdx.x >> 6);
  int lane = threadIdx.x & 63;
  const int QROWS = B_ * H_ * S_;
  u16* ptr; const float* nw; int b, s;
  if (row < QROWS) {
    ptr = qb + (size_t)row * D_; nw = qnw;
    s = row & (S_ - 1); b = row / (H_ * S_);
  } else {
    int r2 = row - QROWS;
    ptr = kb + (size_t)r2 * D_; nw = knw;
    s = r2 & (S_ - 1); b = r2 / (KVH_ * S_);
  }
  int d = lane * 2;
  float x0 = b2f(ptr[d]), x1 = b2f(ptr[d + 1]);
  float ss = x0 * x0 + x1 * x1;
#pragma unroll
  for (int m = 1; m < 64; m <<= 1) ss += __shfl_xor(ss, m);
  float inv = rsqrtf(ss * (1.0f / 128.0f) + 1e-6f);
  x0 = x0 * inv * nw[d]; x1 = x1 * inv * nw[d + 1];
  float p0 = __shfl_xor(x0, 32), p1 = __shfl_xor(x1, 32);
  float r0 = (lane < 32) ? -p0 : p0;
  float r1 = (lane < 32) ? -p1 : p1;
  const float* cp = cosp + ((size_t)b * S_ + s) * D_;
  const float* sp = sinp + ((size_t)b * S_ + s) * D_;
  ptr[d]     = f2b(x0 * cp[d]     + r0 * sp[d]);
  ptr[d + 1] = f2b(x1 * cp[d + 1] + r1 * sp[d + 1]);
}

// ---------------- causal GQA flash attention ----------------
__global__ __launch_bounds__(256, 1) void k_attn(const u16* __restrict__ q,
    const u16* __restrict__ k, const u16* __restrict__ v, u16* __restrict__ out) {
  __shared__ u16 Ks[128 * 136];
  __shared__ u16 Vts[128 * 136];
  __shared__ u16 Ps[128 * 136];
  const int qt = blockIdx.x, bh = blockIdx.y;
  const int b = bh >> 5, h = bh & 31;
  const int kvh = h >> 3;
  const int tid = threadIdx.x, lane = tid & 63, w = tid >> 6;
  const int lc = lane & 15, lk8 = (lane >> 4) * 8, lr4 = (lane >> 4) * 4;
  const u16* qp = q + ((size_t)(b * H_ + h) * S_) * D_;
  const u16* kp = k + ((size_t)(b * KVH_ + kvh) * S_) * D_;
  const u16* vp = v + ((size_t)(b * KVH_ + kvh) * S_) * D_;
  const int q0 = qt * 128;

  bf16x8 aq[2][4];
#pragma unroll
  for (int mi = 0; mi < 2; mi++)
#pragma unroll
    for (int kc = 0; kc < 4; kc++)
      aq[mi][kc] = *reinterpret_cast<const bf16x8*>(
          qp + (size_t)(q0 + w * 32 + mi * 16 + lc) * D_ + kc * 32 + lk8);

  const f32x4 zz = {0.f, 0.f, 0.f, 0.f};
  f32x4 oacc[2][8];
#pragma unroll
  for (int mi = 0; mi < 2; mi++)
#pragma unroll
    for (int dj = 0; dj < 8; dj++) oacc[mi][dj] = zz;
  float mrun[2][4], lrun[2][4];
#pragma unroll
  for (int mi = 0; mi < 2; mi++)
#pragma unroll
    for (int r = 0; r < 4; r++) { mrun[mi][r] = -1e30f; lrun[mi][r] = 0.f; }

  const float scale = 0.08838834764831845f;  // 1/sqrt(128)
  const int srow = tid >> 1, soff = (tid & 1) * 64;

  for (int nt = 0; nt <= qt; nt++) {
    const int n0 = nt * 128;
#pragma unroll
    for (int i = 0; i < 8; i++) {
      bf16x8 kvv = *reinterpret_cast<const bf16x8*>(kp + (size_t)(n0 + srow) * D_ + soff + i * 8);
      *reinterpret_cast<bf16x8*>(Ks + srow * 136 + soff + i * 8) = kvv;
      bf16x8 vv = *reinterpret_cast<const bf16x8*>(vp + (size_t)(n0 + srow) * D_ + soff + i * 8);
#pragma unroll
      for (int e = 0; e < 8; e++)
        Vts[(soff + i * 8 + e) * 136 + srow] = (u16)vv[e];
    }
    __syncthreads();

    f32x4 sacc[2][8];
#pragma unroll
    for (int mi = 0; mi < 2; mi++)
#pragma unroll
      for (int j = 0; j < 8; j++) sacc[mi][j] = zz;
#pragma unroll
    for (int kc = 0; kc < 4; kc++) {
      bf16x8 bk[8];
#pragma unroll
      for (int j = 0; j < 8; j++)
        bk[j] = *reinterpret_cast<const bf16x8*>(Ks + (j * 16 + lc) * 136 + kc * 32 + lk8);
#pragma unroll
      for (int mi = 0; mi < 2; mi++)
#pragma unroll
        for (int j = 0; j < 8; j++)
          sacc[mi][j] = __builtin_amdgcn_mfma_f32_16x16x32_bf16(aq[mi][kc], bk[j], sacc[mi][j], 0, 0, 0);
    }

    const bool diag = (nt == qt);
#pragma unroll
    for (int mi = 0; mi < 2; mi++)
#pragma unroll
      for (int r = 0; r < 4; r++) {
        const int mrow_t = w * 32 + mi * 16 + lr4 + r;
        float t = -1e30f;
#pragma unroll
        for (int j = 0; j < 8; j++) {
          float sv = sacc[mi][j][r] * scale;
          if (diag && (j * 16 + lc > mrow_t)) sv = -1e30f;
          sacc[mi][j][r] = sv;
          t = fmaxf(t, sv);
        }
        t = fmaxf(t, __shfl_xor(t, 1));
        t = fmaxf(t, __shfl_xor(t, 2));
        t = fmaxf(t, __shfl_xor(t, 4));
        t = fmaxf(t, __shfl_xor(t, 8));
        float mn = fmaxf(mrun[mi][r], t);
        float alpha = __expf(mrun[mi][r] - mn);
        mrun[mi][r] = mn;
        lrun[mi][r] *= alpha;
#pragma unroll
        for (int dj = 0; dj < 8; dj++) oacc[mi][dj][r] *= alpha;
        float rs = 0.f;
#pragma unroll
        for (int j = 0; j < 8; j++) {
          float p = __expf(sacc[mi][j][r] - mn);
          rs += p;
          Ps[(w * 32 + mi * 16 + lr4 + r) * 136 + j * 16 + lc] = f2b(p);
        }
        rs += __shfl_xor(rs, 1);
        rs += __shfl_xor(rs, 2);
        rs += __shfl_xor(rs, 4);
        rs += __shfl_xor(rs, 8);
        lrun[mi][r] += rs;
      }

#pragma unroll
    for (int kc = 0; kc < 4; kc++) {
      bf16x8 ap[2];
#pragma unroll
      for (int mi = 0; mi < 2; mi++)
        ap[mi] = *reinterpret_cast<const bf16x8*>(Ps + (w * 32 + mi * 16 + lc) * 136 + kc * 32 + lk8);
      bf16x8 bv[8];
#pragma unroll
      for (int dj = 0; dj < 8; dj++)
        bv[dj] = *reinterpret_cast<const bf16x8*>(Vts + (dj * 16 + lc) * 136 + kc * 32 + lk8);
#pragma unroll
      for (int mi = 0; mi < 2; mi++)
#pragma unroll
        for (int dj = 0; dj < 8; dj++)
          oacc[mi][dj] = __builtin_amdgcn_mfma_f32_16x16x32_bf16(ap[mi], bv[dj], oacc[mi][dj], 0, 0, 0);
    }
    __syncthreads();
  }

#pragma unroll
  for (int mi = 0; mi < 2; mi++)
#pragma unroll
    for (int dj = 0; dj < 8; dj++)
#pragma unroll
      for (int r = 0; r < 4; r++) {
        int sg = q0 + w * 32 + mi * 16 + lr4 + r;
        int d = dj * 16 + lc;
        float o = oacc[mi][dj][r] / lrun[mi][r];
        out[((size_t)b * S_ + sg) * NQ_ + h * D_ + d] = f2b(o);
      }
}

extern "C" void kernel_launch(void* const* d_in, const int* in_sizes, int n_in,
                              void* d_out, int out_size, void* d_ws, size_t ws_size,
                              hipStream_t stream) {
  const float* hidden = (const float*)d_in[0];
  const float* cosp   = (const float*)d_in[1];
  const float* sinp   = (const float*)d_in[2];
  const float* q_w    = (const float*)d_in[3];
  const float* k_w    = (const float*)d_in[4];
  const float* v_w    = (const float*)d_in[5];
  const float* o_w    = (const float*)d_in[6];
  const float* qnw    = (const float*)d_in[7];
  const float* knw    = (const float*)d_in[8];

  char* p = (char*)d_ws;
  u16* hb  = (u16*)p; p += (size_t)M_ * HID_ * 2;
  u16* qwt = (u16*)p; p += (size_t)NQ_ * HID_ * 2;
  u16* kwt = (u16*)p; p += (size_t)NKV_ * HID_ * 2;
  u16* vwt = (u16*)p; p += (size_t)NKV_ * HID_ * 2;
  u16* owt = (u16*)p; p += (size_t)HID_ * NQ_ * 2;
  u16* qb  = (u16*)p; p += (size_t)B_ * H_ * S_ * D_ * 2;
  u16* kb  = (u16*)p; p += (size_t)B_ * KVH_ * S_ * D_ * 2;
  u16* vb  = (u16*)p; p += (size_t)B_ * KVH_ * S_ * D_ * 2;
  u16* ab  = (u16*)p; p += (size_t)M_ * NQ_ * 2;

  k_cvt<<<2048, 256, 0, stream>>>(hidden, hb, M_ * HID_ / 4);
  k_transpose<<<dim3(NQ_ / 64, HID_ / 64), 256, 0, stream>>>(q_w, qwt, HID_, NQ_);
  k_transpose<<<dim3(NKV_ / 64, HID_ / 64), 256, 0, stream>>>(k_w, kwt, HID_, NKV_);
  k_transpose<<<dim3(NKV_ / 64, HID_ / 64), 256, 0, stream>>>(v_w, vwt, HID_, NKV_);
  k_transpose<<<dim3(HID_ / 64, NQ_ / 64), 256, 0, stream>>>(o_w, owt, NQ_, HID_);
  k_gemm_qkv<<<dim3(M_ / 128, 40), 256, 0, stream>>>(hb, qwt, kwt, vwt, qb, kb, vb);
  k_norm_rope<<<(B_ * H_ * S_ + B_ * KVH_ * S_) / 4, 256, 0, stream>>>(qb, kb, cosp, sinp, qnw, knw);
  k_attn<<<dim3(S_ / 128, B_ * H_), 256, 0, stream>>>(qb, kb, vb, ab);
  k_gemm_o<<<dim3(M_ / 128, HID_ / 128), 256, 0, stream>>>(ab, owt, (float*)d_out);
}

// Round 2
// 436.471 us; speedup vs baseline: 2.2477x; 2.2477x over previous
//
#include <hip/hip_runtime.h>
#include <hip/hip_bf16.h>

typedef unsigned short u16;
typedef __attribute__((ext_vector_type(4))) float f32x4;
typedef __attribute__((ext_vector_type(8))) short bf16x8;

#define B_ 2
#define S_ 2048
#define HID_ 2048
#define H_ 32
#define KVH_ 4
#define D_ 128
#define M_ 4096
#define NQ_ 4096
#define NKV_ 512

typedef const __attribute__((address_space(1))) void gconst_void;
typedef __attribute__((address_space(3))) void lds_void;

static __device__ __forceinline__ void gload_lds16(const void* g, void* l) {
  __builtin_amdgcn_global_load_lds((gconst_void*)g, (lds_void*)l, 16, 0, 0);
}

static __device__ __forceinline__ u16 f2b(float f) {
  union { float f; unsigned i; } x; x.f = f;
  return (u16)((x.i + 0x7fffu + ((x.i >> 16) & 1u)) >> 16);
}
static __device__ __forceinline__ float b2f(u16 u) {
  union { unsigned i; float f; } x; x.i = ((unsigned)u) << 16;
  return x.f;
}

// ---------------- fp32 -> bf16 elementwise ----------------
__global__ void k_cvt(const float* __restrict__ in, u16* __restrict__ out, int n4) {
  int i = blockIdx.x * blockDim.x + threadIdx.x;
  int stride = gridDim.x * blockDim.x;
  for (; i < n4; i += stride) {
    float4 v = reinterpret_cast<const float4*>(in)[i];
    ushort4 o;
    o.x = f2b(v.x); o.y = f2b(v.y); o.z = f2b(v.z); o.w = f2b(v.w);
    reinterpret_cast<ushort4*>(out)[i] = o;
  }
}

// ---------------- W fp32 [K][N] -> Wt bf16 [N][K] ----------------
__global__ __launch_bounds__(256) void k_transpose(const float* __restrict__ W,
                                                   u16* __restrict__ Wt, int K, int N) {
  __shared__ u16 t[64][72];
  int n0 = blockIdx.x * 64, k0 = blockIdx.y * 64;
  int tid = threadIdx.x;
  int r = tid >> 4;          // 0..15
  int c4 = (tid & 15) * 4;   // 0..60
#pragma unroll
  for (int i = 0; i < 4; i++) {
    int k = r + i * 16;
    float4 v = *reinterpret_cast<const float4*>(W + (size_t)(k0 + k) * N + n0 + c4);
    t[k][c4 + 0] = f2b(v.x); t[k][c4 + 1] = f2b(v.y);
    t[k][c4 + 2] = f2b(v.z); t[k][c4 + 3] = f2b(v.w);
  }
  __syncthreads();
#pragma unroll
  for (int i = 0; i < 4; i++) {
    int n = r + i * 16;
    ushort4 o;
    o.x = t[c4 + 0][n]; o.y = t[c4 + 1][n]; o.z = t[c4 + 2][n]; o.w = t[c4 + 3][n];
    *reinterpret_cast<ushort4*>(Wt + (size_t)(n0 + n) * K + k0 + c4) = o;
  }
}

// ---- 128x128 bf16 GEMM core (A [M][K], Bt [N][K]), global_load_lds staging ----
__device__ __forceinline__ void gemm_core(const u16* __restrict__ A, const u16* __restrict__ Bt,
                                          int K, int m0, int n0,
                                          u16* As, u16* Bs, f32x4 (&acc)[4][4]) {
  const int tid = threadIdx.x;
  const int lane = tid & 63;
  const int wid = tid >> 6;
  const int wr = wid >> 1, wc = wid & 1;
  const int lrow = lane & 15;
  const int lk8 = (lane >> 4) * 8;
  const f32x4 zz = {0.f, 0.f, 0.f, 0.f};
#pragma unroll
  for (int i = 0; i < 4; i++)
#pragma unroll
    for (int j = 0; j < 4; j++) acc[i][j] = zz;

  const int srow = tid >> 3;       // 0..31
  const int scol = (tid & 7) * 8;  // 0..56 (u16 units)
  const u16* ag = A + (size_t)(m0 + srow) * K + scol;
  const u16* bg = Bt + (size_t)(n0 + srow) * K + scol;
  u16* al = As + srow * 64 + scol;
  u16* bl = Bs + srow * 64 + scol;

  for (int k0 = 0; k0 < K; k0 += 64) {
#pragma unroll
    for (int rep = 0; rep < 4; rep++) {
      gload_lds16(ag + (size_t)rep * 32 * K + k0, al + rep * 32 * 64);
      gload_lds16(bg + (size_t)rep * 32 * K + k0, bl + rep * 32 * 64);
    }
    __syncthreads();
#pragma unroll
    for (int kc = 0; kc < 2; kc++) {
      bf16x8 af[4], bfr[4];
#pragma unroll
      for (int i = 0; i < 4; i++)
        af[i] = *reinterpret_cast<const bf16x8*>(As + (wr * 64 + i * 16 + lrow) * 64 + kc * 32 + lk8);
#pragma unroll
      for (int j = 0; j < 4; j++)
        bfr[j] = *reinterpret_cast<const bf16x8*>(Bs + (wc * 64 + j * 16 + lrow) * 64 + kc * 32 + lk8);
#pragma unroll
      for (int i = 0; i < 4; i++)
#pragma unroll
        for (int j = 0; j < 4; j++)
          acc[i][j] = __builtin_amdgcn_mfma_f32_16x16x32_bf16(af[i], bfr[j], acc[i][j], 0, 0, 0);
    }
    __syncthreads();
  }
}

// ---------------- QKV projection (V written transposed [B][KVH][D][S]) ----------------
__global__ __launch_bounds__(256, 2) void k_gemm_qkv(const u16* __restrict__ hb,
    const u16* __restrict__ qwt, const u16* __restrict__ kwt, const u16* __restrict__ vwt,
    u16* __restrict__ qb, u16* __restrict__ kb, u16* __restrict__ vb) {
  __shared__ u16 As[128 * 64], Bs[128 * 64];
  int mt = blockIdx.x, nt = blockIdx.y;
  const u16* Bt;
  if (nt < 32)      Bt = qwt;
  else if (nt < 36) Bt = kwt;
  else              Bt = vwt;
  int head = (nt < 32) ? nt : ((nt < 36) ? nt - 32 : nt - 36);
  f32x4 acc[4][4];
  gemm_core(hb, Bt, HID_, mt * 128, head * 128, As, Bs, acc);
  const int lane = threadIdx.x & 63;
  const int wid = threadIdx.x >> 6;
  const int wr = wid >> 1, wc = wid & 1;
  const int lr4 = (lane >> 4) * 4, lc = lane & 15;
#pragma unroll
  for (int i = 0; i < 4; i++)
#pragma unroll
    for (int j = 0; j < 4; j++)
#pragma unroll
      for (int r = 0; r < 4; r++) {
        int m = mt * 128 + wr * 64 + i * 16 + lr4 + r;
        int d = wc * 64 + j * 16 + lc;
        int b = m >> 11, s = m & (S_ - 1);
        u16 val = f2b(acc[i][j][r]);
        if (nt < 32) {
          qb[(((size_t)b * H_ + head) * S_ + s) * D_ + d] = val;
        } else if (nt < 36) {
          kb[(((size_t)b * KVH_ + head) * S_ + s) * D_ + d] = val;
        } else {
          vb[(((size_t)b * KVH_ + head) * D_ + d) * S_ + s] = val;  // transposed
        }
      }
}

// ---------------- O projection ----------------
__global__ __launch_bounds__(256, 2) void k_gemm_o(const u16* __restrict__ ab,
    const u16* __restrict__ owt, float* __restrict__ out) {
  __shared__ u16 As[128 * 64], Bs[128 * 64];
  int mt = blockIdx.x, nt = blockIdx.y;
  f32x4 acc[4][4];
  gemm_core(ab, owt, NQ_, mt * 128, nt * 128, As, Bs, acc);
  const int lane = threadIdx.x & 63;
  const int wid = threadIdx.x >> 6;
  const int wr = wid >> 1, wc = wid & 1;
  const int lr4 = (lane >> 4) * 4, lc = lane & 15;
#pragma unroll
  for (int i = 0; i < 4; i++)
#pragma unroll
    for (int j = 0; j < 4; j++)
#pragma unroll
      for (int r = 0; r < 4; r++) {
        int m = mt * 128 + wr * 64 + i * 16 + lr4 + r;
        int n = nt * 128 + wc * 64 + j * 16 + lc;
        out[(size_t)m * HID_ + n] = acc[i][j][r];
      }
}

// ---------------- RMSNorm + RoPE (in place on q/k) ----------------
__global__ __launch_bounds__(256) void k_norm_rope(u16* __restrict__ qb, u16* __restrict__ kb,
    const float* __restrict__ cosp, const float* __restrict__ sinp,
    const float* __restrict__ qnw, const float* __restrict__ knw) {
  int row = blockIdx.x * 4 + (threadIdx.x >> 6);
  int lane = threadIdx.x & 63;
  const int QROWS = B_ * H_ * S_;
  u16* ptr; const float* nw; int b, s;
  if (row < QROWS) {
    ptr = qb + (size_t)row * D_; nw = qnw;
    s = row & (S_ - 1); b = row / (H_ * S_);
  } else {
    int r2 = row - QROWS;
    ptr = kb + (size_t)r2 * D_; nw = knw;
    s = r2 & (S_ - 1); b = r2 / (KVH_ * S_);
  }
  int d = lane * 2;
  float x0 = b2f(ptr[d]), x1 = b2f(ptr[d + 1]);
  float ss = x0 * x0 + x1 * x1;
#pragma unroll
  for (int m = 1; m < 64; m <<= 1) ss += __shfl_xor(ss, m);
  float inv = rsqrtf(ss * (1.0f / 128.0f) + 1e-6f);
  x0 = x0 * inv * nw[d]; x1 = x1 * inv * nw[d + 1];
  float p0 = __shfl_xor(x0, 32), p1 = __shfl_xor(x1, 32);
  float r0 = (lane < 32) ? -p0 : p0;
  float r1 = (lane < 32) ? -p1 : p1;
  const float* cp = cosp + ((size_t)b * S_ + s) * D_;
  const float* sp = sinp + ((size_t)b * S_ + s) * D_;
  ptr[d]     = f2b(x0 * cp[d]     + r0 * sp[d]);
  ptr[d + 1] = f2b(x1 * cp[d + 1] + r1 * sp[d + 1]);
}

// ---------------- causal GQA flash attention ----------------
// grid: (8, B*H). Block x handles q-tiles {x, 15-x}: 17 tile-iters each (balanced).
// LDS: KP = K tile then reused for P tile; Vt = V^T tile (staged from global V^T).
__global__ __launch_bounds__(256, 2) void k_attn(const u16* __restrict__ q,
    const u16* __restrict__ k, const u16* __restrict__ vt, u16* __restrict__ out) {
  __shared__ u16 KP[128 * 136];
  __shared__ u16 Vt[128 * 136];
  const int bh = blockIdx.y;
  const int b = bh >> 5, h = bh & 31;
  const int kvh = h >> 3;
  const int tid = threadIdx.x, lane = tid & 63, w = tid >> 6;
  const int lc = lane & 15, lk8 = (lane >> 4) * 8, lr4 = (lane >> 4) * 4;
  const u16* qp  = q  + ((size_t)(b * H_ + h) * S_) * D_;
  const u16* kp  = k  + ((size_t)(b * KVH_ + kvh) * S_) * D_;
  const u16* vtp = vt + ((size_t)(b * KVH_ + kvh) * D_) * S_;

  // staging pattern: 16-lane groups read 256B contiguous
  const int st_row = tid >> 4;        // 0..15
  const int st_col = (tid & 15) * 8;  // 0..120 (u16)

  const float scale = 0.08838834764831845f;  // 1/sqrt(128)
  const f32x4 zz = {0.f, 0.f, 0.f, 0.f};

  for (int half = 0; half < 2; half++) {
    const int qt = half ? (2 * (int)gridDim.x - 1 - (int)blockIdx.x) : (int)blockIdx.x;
    const int q0 = qt * 128;

    bf16x8 aq[2][4];
#pragma unroll
    for (int mi = 0; mi < 2; mi++)
#pragma unroll
      for (int kc = 0; kc < 4; kc++)
        aq[mi][kc] = *reinterpret_cast<const bf16x8*>(
            qp + (size_t)(q0 + w * 32 + mi * 16 + lc) * D_ + kc * 32 + lk8);

    f32x4 oacc[2][8];
#pragma unroll
    for (int mi = 0; mi < 2; mi++)
#pragma unroll
      for (int dj = 0; dj < 8; dj++) oacc[mi][dj] = zz;
    float mrun[2][4], lrun[2][4];
#pragma unroll
    for (int mi = 0; mi < 2; mi++)
#pragma unroll
      for (int r = 0; r < 4; r++) { mrun[mi][r] = -1e30f; lrun[mi][r] = 0.f; }

    for (int nt = 0; nt <= qt; nt++) {
      const int n0 = nt * 128;
      __syncthreads();  // A: previous PV (or previous half) done with KP/Vt
#pragma unroll
      for (int rep = 0; rep < 8; rep++) {
        int row = rep * 16 + st_row;
        *reinterpret_cast<bf16x8*>(KP + row * 136 + st_col) =
            *reinterpret_cast<const bf16x8*>(kp + (size_t)(n0 + row) * D_ + st_col);
        *reinterpret_cast<bf16x8*>(Vt + row * 136 + st_col) =
            *reinterpret_cast<const bf16x8*>(vtp + (size_t)row * S_ + n0 + st_col);
      }
      __syncthreads();  // B: tiles staged

      f32x4 sacc[2][8];
#pragma unroll
      for (int mi = 0; mi < 2; mi++)
#pragma unroll
        for (int j = 0; j < 8; j++) sacc[mi][j] = zz;
#pragma unroll
      for (int kc = 0; kc < 4; kc++) {
        bf16x8 bk[8];
#pragma unroll
        for (int j = 0; j < 8; j++)
          bk[j] = *reinterpret_cast<const bf16x8*>(KP + (j * 16 + lc) * 136 + kc * 32 + lk8);
#pragma unroll
        for (int mi = 0; mi < 2; mi++)
#pragma unroll
          for (int j = 0; j < 8; j++)
            sacc[mi][j] = __builtin_amdgcn_mfma_f32_16x16x32_bf16(aq[mi][kc], bk[j], sacc[mi][j], 0, 0, 0);
      }
      __syncthreads();  // C: all KP (K) reads done before P overwrite

      const bool diag = (nt == qt);
#pragma unroll
      for (int mi = 0; mi < 2; mi++)
#pragma unroll
        for (int r = 0; r < 4; r++) {
          const int mrow_t = w * 32 + mi * 16 + lr4 + r;
          float t = -1e30f;
#pragma unroll
          for (int j = 0; j < 8; j++) {
            float sv = sacc[mi][j][r] * scale;
            if (diag && (j * 16 + lc > mrow_t)) sv = -1e30f;
            sacc[mi][j][r] = sv;
            t = fmaxf(t, sv);
          }
          t = fmaxf(t, __shfl_xor(t, 1));
          t = fmaxf(t, __shfl_xor(t, 2));
          t = fmaxf(t, __shfl_xor(t, 4));
          t = fmaxf(t, __shfl_xor(t, 8));
          float mn = fmaxf(mrun[mi][r], t);
          float alpha = __expf(mrun[mi][r] - mn);
          mrun[mi][r] = mn;
          lrun[mi][r] *= alpha;
#pragma unroll
          for (int dj = 0; dj < 8; dj++) oacc[mi][dj][r] *= alpha;
          float rs = 0.f;
#pragma unroll
          for (int j = 0; j < 8; j++) {
            float p = __expf(sacc[mi][j][r] - mn);
            rs += p;
            KP[(w * 32 + mi * 16 + lr4 + r) * 136 + j * 16 + lc] = f2b(p);  // P into KP
          }
          rs += __shfl_xor(rs, 1);
          rs += __shfl_xor(rs, 2);
          rs += __shfl_xor(rs, 4);
          rs += __shfl_xor(rs, 8);
          lrun[mi][r] += rs;
        }
      __syncthreads();  // D: P visible

#pragma unroll
      for (int kc = 0; kc < 4; kc++) {
        bf16x8 ap[2];
#pragma unroll
        for (int mi = 0; mi < 2; mi++)
          ap[mi] = *reinterpret_cast<const bf16x8*>(KP + (w * 32 + mi * 16 + lc) * 136 + kc * 32 + lk8);
        bf16x8 bv[8];
#pragma unroll
        for (int dj = 0; dj < 8; dj++)
          bv[dj] = *reinterpret_cast<const bf16x8*>(Vt + (dj * 16 + lc) * 136 + kc * 32 + lk8);
#pragma unroll
        for (int mi = 0; mi < 2; mi++)
#pragma unroll
          for (int dj = 0; dj < 8; dj++)
            oacc[mi][dj] = __builtin_amdgcn_mfma_f32_16x16x32_bf16(ap[mi], bv[dj], oacc[mi][dj], 0, 0, 0);
      }
    }

#pragma unroll
    for (int mi = 0; mi < 2; mi++)
#pragma unroll
      for (int dj = 0; dj < 8; dj++)
#pragma unroll
        for (int r = 0; r < 4; r++) {
          int sg = q0 + w * 32 + mi * 16 + lr4 + r;
          int d = dj * 16 + lc;
          float o = oacc[mi][dj][r] / lrun[mi][r];
          out[((size_t)b * S_ + sg) * NQ_ + h * D_ + d] = f2b(o);
        }
  }
}

extern "C" void kernel_launch(void* const* d_in, const int* in_sizes, int n_in,
                              void* d_out, int out_size, void* d_ws, size_t ws_size,
                              hipStream_t stream) {
  const float* hidden = (const float*)d_in[0];
  const float* cosp   = (const float*)d_in[1];
  const float* sinp   = (const float*)d_in[2];
  const float* q_w    = (const float*)d_in[3];
  const float* k_w    = (const float*)d_in[4];
  const float* v_w    = (const float*)d_in[5];
  const float* o_w    = (const float*)d_in[6];
  const float* qnw    = (const float*)d_in[7];
  const float* knw    = (const float*)d_in[8];

  char* p = (char*)d_ws;
  u16* hb  = (u16*)p; p += (size_t)M_ * HID_ * 2;
  u16* qwt = (u16*)p; p += (size_t)NQ_ * HID_ * 2;
  u16* kwt = (u16*)p; p += (size_t)NKV_ * HID_ * 2;
  u16* vwt = (u16*)p; p += (size_t)NKV_ * HID_ * 2;
  u16* owt = (u16*)p; p += (size_t)HID_ * NQ_ * 2;
  u16* qb  = (u16*)p; p += (size_t)B_ * H_ * S_ * D_ * 2;
  u16* kb  = (u16*)p; p += (size_t)B_ * KVH_ * S_ * D_ * 2;
  u16* vb  = (u16*)p; p += (size_t)B_ * KVH_ * S_ * D_ * 2;  // V^T [B][KVH][D][S]
  u16* ab  = (u16*)p; p += (size_t)M_ * NQ_ * 2;

  k_cvt<<<2048, 256, 0, stream>>>(hidden, hb, M_ * HID_ / 4);
  k_transpose<<<dim3(NQ_ / 64, HID_ / 64), 256, 0, stream>>>(q_w, qwt, HID_, NQ_);
  k_transpose<<<dim3(NKV_ / 64, HID_ / 64), 256, 0, stream>>>(k_w, kwt, HID_, NKV_);
  k_transpose<<<dim3(NKV_ / 64, HID_ / 64), 256, 0, stream>>>(v_w, vwt, HID_, NKV_);
  k_transpose<<<dim3(HID_ / 64, NQ_ / 64), 256, 0, stream>>>(o_w, owt, NQ_, HID_);
  k_gemm_qkv<<<dim3(M_ / 128, 40), 256, 0, stream>>>(hb, qwt, kwt, vwt, qb, kb, vb);
  k_norm_rope<<<(B_ * H_ * S_ + B_ * KVH_ * S_) / 4, 256, 0, stream>>>(qb, kb, cosp, sinp, qnw, knw);
  k_attn<<<dim3(8, B_ * H_), 256, 0, stream>>>(qb, kb, vb, ab);
  k_gemm_o<<<dim3(M_ / 128, HID_ / 128), 256, 0, stream>>>(ab, owt, (float*)d_out);
}

// Round 3
// 419.847 us; speedup vs baseline: 2.3367x; 1.0396x over previous
//
#include <hip/hip_runtime.h>
#include <hip/hip_bf16.h>

typedef unsigned short u16;
typedef __attribute__((ext_vector_type(4))) float f32x4;
typedef __attribute__((ext_vector_type(8))) short bf16x8;

#define B_ 2
#define S_ 2048
#define HID_ 2048
#define H_ 32
#define KVH_ 4
#define D_ 128
#define M_ 4096
#define NQ_ 4096
#define NKV_ 512

typedef const __attribute__((address_space(1))) void gconst_void;
typedef __attribute__((address_space(3))) void lds_void;

static __device__ __forceinline__ void gload_lds16(const void* g, void* l) {
  __builtin_amdgcn_global_load_lds((gconst_void*)g, (lds_void*)l, 16, 0, 0);
}

// barrier that drains LDS ops only (keeps global_load_lds in flight)
static __device__ __forceinline__ void bar_lds() {
  asm volatile("s_waitcnt lgkmcnt(0)" ::: "memory");
  __builtin_amdgcn_sched_barrier(0);
  __builtin_amdgcn_s_barrier();
  __builtin_amdgcn_sched_barrier(0);
}

static __device__ __forceinline__ u16 f2b(float f) {
  union { float f; unsigned i; } x; x.f = f;
  return (u16)((x.i + 0x7fffu + ((x.i >> 16) & 1u)) >> 16);
}
static __device__ __forceinline__ float b2f(u16 u) {
  union { unsigned i; float f; } x; x.i = ((unsigned)u) << 16;
  return x.f;
}

// ---------------- fp32 -> bf16 elementwise ----------------
__global__ void k_cvt(const float* __restrict__ in, u16* __restrict__ out, int n4) {
  int i = blockIdx.x * blockDim.x + threadIdx.x;
  int stride = gridDim.x * blockDim.x;
  for (; i < n4; i += stride) {
    float4 v = reinterpret_cast<const float4*>(in)[i];
    ushort4 o;
    o.x = f2b(v.x); o.y = f2b(v.y); o.z = f2b(v.z); o.w = f2b(v.w);
    reinterpret_cast<ushort4*>(out)[i] = o;
  }
}

// ---------------- W fp32 [K][N] -> Wt bf16 [N][K] ----------------
__global__ __launch_bounds__(256) void k_transpose(const float* __restrict__ W,
                                                   u16* __restrict__ Wt, int K, int N) {
  __shared__ u16 t[64][72];
  int n0 = blockIdx.x * 64, k0 = blockIdx.y * 64;
  int tid = threadIdx.x;
  int r = tid >> 4;
  int c4 = (tid & 15) * 4;
#pragma unroll
  for (int i = 0; i < 4; i++) {
    int k = r + i * 16;
    float4 v = *reinterpret_cast<const float4*>(W + (size_t)(k0 + k) * N + n0 + c4);
    t[k][c4 + 0] = f2b(v.x); t[k][c4 + 1] = f2b(v.y);
    t[k][c4 + 2] = f2b(v.z); t[k][c4 + 3] = f2b(v.w);
  }
  __syncthreads();
#pragma unroll
  for (int i = 0; i < 4; i++) {
    int n = r + i * 16;
    ushort4 o;
    o.x = t[c4 + 0][n]; o.y = t[c4 + 1][n]; o.z = t[c4 + 2][n]; o.w = t[c4 + 3][n];
    *reinterpret_cast<ushort4*>(Wt + (size_t)(n0 + n) * K + k0 + c4) = o;
  }
}

// ---- 128x128 bf16 GEMM core, 2-phase dbuf + swizzled global_load_lds staging ----
// LDS tiles [128 rows][64 u16 cols] = 8x 16B slots/row, slot swizzle: c16 ^= row&7.
__device__ __forceinline__ void gemm_core(const u16* __restrict__ A, const u16* __restrict__ Bt,
                                          int K, int m0, int n0,
                                          u16* As, u16* Bs, f32x4 (&acc)[4][4]) {
  const int tid = threadIdx.x;
  const int lane = tid & 63;
  const int wid = tid >> 6;
  const int wr = wid >> 1, wc = wid & 1;
  const int lrow = lane & 15;
  const int hi = lane >> 4;
  const f32x4 zz = {0.f, 0.f, 0.f, 0.f};
#pragma unroll
  for (int i = 0; i < 4; i++)
#pragma unroll
    for (int j = 0; j < 4; j++) acc[i][j] = zz;

  const int srow = tid >> 3;                 // 0..31 (row within 32-row rep)
  const int sc16 = tid & 7;                  // slot within row
  const int nk = K >> 6;
  int cur = 0;

  // prologue: stage tile 0 into buf 0
#pragma unroll
  for (int rep = 0; rep < 4; rep++) {
    int row = rep * 32 + srow;
    int gcol = ((sc16 ^ (row & 7)) << 3);
    gload_lds16(A + (size_t)(m0 + row) * K + gcol, As + row * 64 + sc16 * 8);
    gload_lds16(Bt + (size_t)(n0 + row) * K + gcol, Bs + row * 64 + sc16 * 8);
  }
  __syncthreads();

  for (int t = 0; t < nk; t++) {
    if (t + 1 < nk) {
      int nxt = cur ^ 1;
      int kb = (t + 1) << 6;
#pragma unroll
      for (int rep = 0; rep < 4; rep++) {
        int row = rep * 32 + srow;
        int gcol = kb + ((sc16 ^ (row & 7)) << 3);
        gload_lds16(A + (size_t)(m0 + row) * K + gcol, As + nxt * 8192 + row * 64 + sc16 * 8);
        gload_lds16(Bt + (size_t)(n0 + row) * K + gcol, Bs + nxt * 8192 + row * 64 + sc16 * 8);
      }
    }
    const u16* Ac = As + cur * 8192;
    const u16* Bc = Bs + cur * 8192;
#pragma unroll
    for (int kc = 0; kc < 2; kc++) {
      bf16x8 af[4], bfr[4];
#pragma unroll
      for (int i = 0; i < 4; i++) {
        int row = wr * 64 + i * 16 + lrow;
        af[i] = *reinterpret_cast<const bf16x8*>(Ac + row * 64 + ((((kc << 2) + hi) ^ (row & 7)) << 3));
      }
#pragma unroll
      for (int j = 0; j < 4; j++) {
        int row = wc * 64 + j * 16 + lrow;
        bfr[j] = *reinterpret_cast<const bf16x8*>(Bc + row * 64 + ((((kc << 2) + hi) ^ (row & 7)) << 3));
      }
#pragma unroll
      for (int i = 0; i < 4; i++)
#pragma unroll
        for (int j = 0; j < 4; j++)
          acc[i][j] = __builtin_amdgcn_mfma_f32_16x16x32_bf16(af[i], bfr[j], acc[i][j], 0, 0, 0);
    }
    __syncthreads();
    cur ^= 1;
  }
}

// ---------------- QKV projection (V written transposed [B][KVH][D][S]) ----------------
__global__ __launch_bounds__(256, 2) void k_gemm_qkv(const u16* __restrict__ hb,
    const u16* __restrict__ qwt, const u16* __restrict__ kwt, const u16* __restrict__ vwt,
    u16* __restrict__ qb, u16* __restrict__ kb, u16* __restrict__ vb) {
  __shared__ u16 As[2 * 128 * 64], Bs[2 * 128 * 64];
  int mt = blockIdx.x, nt = blockIdx.y;
  const u16* Bt;
  if (nt < 32)      Bt = qwt;
  else if (nt < 36) Bt = kwt;
  else              Bt = vwt;
  int head = (nt < 32) ? nt : ((nt < 36) ? nt - 32 : nt - 36);
  f32x4 acc[4][4];
  gemm_core(hb, Bt, HID_, mt * 128, head * 128, As, Bs, acc);
  const int lane = threadIdx.x & 63;
  const int wid = threadIdx.x >> 6;
  const int wr = wid >> 1, wc = wid & 1;
  const int lr4 = (lane >> 4) * 4, lc = lane & 15;
#pragma unroll
  for (int i = 0; i < 4; i++)
#pragma unroll
    for (int j = 0; j < 4; j++)
#pragma unroll
      for (int r = 0; r < 4; r++) {
        int m = mt * 128 + wr * 64 + i * 16 + lr4 + r;
        int d = wc * 64 + j * 16 + lc;
        int b = m >> 11, s = m & (S_ - 1);
        u16 val = f2b(acc[i][j][r]);
        if (nt < 32) {
          qb[(((size_t)b * H_ + head) * S_ + s) * D_ + d] = val;
        } else if (nt < 36) {
          kb[(((size_t)b * KVH_ + head) * S_ + s) * D_ + d] = val;
        } else {
          vb[(((size_t)b * KVH_ + head) * D_ + d) * S_ + s] = val;  // transposed
        }
      }
}

// ---------------- O projection ----------------
__global__ __launch_bounds__(256, 2) void k_gemm_o(const u16* __restrict__ ab,
    const u16* __restrict__ owt, float* __restrict__ out) {
  __shared__ u16 As[2 * 128 * 64], Bs[2 * 128 * 64];
  int mt = blockIdx.x, nt = blockIdx.y;
  f32x4 acc[4][4];
  gemm_core(ab, owt, NQ_, mt * 128, nt * 128, As, Bs, acc);
  const int lane = threadIdx.x & 63;
  const int wid = threadIdx.x >> 6;
  const int wr = wid >> 1, wc = wid & 1;
  const int lr4 = (lane >> 4) * 4, lc = lane & 15;
#pragma unroll
  for (int i = 0; i < 4; i++)
#pragma unroll
    for (int j = 0; j < 4; j++)
#pragma unroll
      for (int r = 0; r < 4; r++) {
        int m = mt * 128 + wr * 64 + i * 16 + lr4 + r;
        int n = nt * 128 + wc * 64 + j * 16 + lc;
        out[(size_t)m * HID_ + n] = acc[i][j][r];
      }
}

// ---------------- RMSNorm + RoPE (in place on q/k) ----------------
__global__ __launch_bounds__(256) void k_norm_rope(u16* __restrict__ qb, u16* __restrict__ kb,
    const float* __restrict__ cosp, const float* __restrict__ sinp,
    const float* __restrict__ qnw, const float* __restrict__ knw) {
  int row = blockIdx.x * 4 + (threadIdx.x >> 6);
  int lane = threadIdx.x & 63;
  const int QROWS = B_ * H_ * S_;
  u16* ptr; const float* nw; int b, s;
  if (row < QROWS) {
    ptr = qb + (size_t)row * D_; nw = qnw;
    s = row & (S_ - 1); b = row / (H_ * S_);
  } else {
    int r2 = row - QROWS;
    ptr = kb + (size_t)r2 * D_; nw = knw;
    s = r2 & (S_ - 1); b = r2 / (KVH_ * S_);
  }
  int d = lane * 2;
  float x0 = b2f(ptr[d]), x1 = b2f(ptr[d + 1]);
  float ss = x0 * x0 + x1 * x1;
#pragma unroll
  for (int m = 1; m < 64; m <<= 1) ss += __shfl_xor(ss, m);
  float inv = rsqrtf(ss * (1.0f / 128.0f) + 1e-6f);
  x0 = x0 * inv * nw[d]; x1 = x1 * inv * nw[d + 1];
  float p0 = __shfl_xor(x0, 32), p1 = __shfl_xor(x1, 32);
  float r0 = (lane < 32) ? -p0 : p0;
  float r1 = (lane < 32) ? -p1 : p1;
  const float* cp = cosp + ((size_t)b * S_ + s) * D_;
  const float* sp = sinp + ((size_t)b * S_ + s) * D_;
  ptr[d]     = f2b(x0 * cp[d]     + r0 * sp[d]);
  ptr[d + 1] = f2b(x1 * cp[d + 1] + r1 * sp[d + 1]);
}

// ---------------- causal GQA flash attention ----------------
// grid (8, B*H); block x handles q-tiles {x, 15-x} (balanced: 34 kv-iters each).
// KVBLK=64, double-buffered async staging via global_load_lds, XOR-swizzled LDS.
// Kb[cur] (64x128) is reused as P (128x64) after QK^T. LDS = 64 KB -> 2 blocks/CU.
__global__ __launch_bounds__(256, 2) void k_attn(const u16* __restrict__ q,
    const u16* __restrict__ k, const u16* __restrict__ vt, u16* __restrict__ out) {
  __shared__ u16 Kb[2 * 64 * 128];
  __shared__ u16 Vb[2 * 128 * 64];
  const int bh = blockIdx.y;
  const int b = bh >> 5, h = bh & 31;
  const int kvh = h >> 3;
  const int tid = threadIdx.x, lane = tid & 63, w = tid >> 6;
  const int lc = lane & 15, hi = lane >> 4;
  const int lk8 = hi * 8, lr4 = hi * 4;
  const u16* qp  = q  + ((size_t)(b * H_ + h) * S_) * D_;
  const u16* kp  = k  + ((size_t)(b * KVH_ + kvh) * S_) * D_;
  const u16* vtp = vt + ((size_t)(b * KVH_ + kvh) * D_) * S_;

  const float scale = 0.08838834764831845f;  // 1/sqrt(128)
  const f32x4 zz = {0.f, 0.f, 0.f, 0.f};

  for (int half = 0; half < 2; half++) {
    const int qt = half ? (15 - (int)blockIdx.x) : (int)blockIdx.x;
    const int q0 = qt * 128;
    const int last = 2 * qt + 1;

    bf16x8 aq[2][4];
#pragma unroll
    for (int mi = 0; mi < 2; mi++)
#pragma unroll
      for (int kc = 0; kc < 4; kc++)
        aq[mi][kc] = *reinterpret_cast<const bf16x8*>(
            qp + (size_t)(q0 + w * 32 + mi * 16 + lc) * D_ + kc * 32 + lk8);

    f32x4 oacc[2][8];
#pragma unroll
    for (int mi = 0; mi < 2; mi++)
#pragma unroll
      for (int dj = 0; dj < 8; dj++) oacc[mi][dj] = zz;
    float mrun[2][4], lrun[2][4];
#pragma unroll
    for (int mi = 0; mi < 2; mi++)
#pragma unroll
      for (int r = 0; r < 4; r++) { mrun[mi][r] = -1e30f; lrun[mi][r] = 0.f; }

    // prologue: stage kv-tile 0 into buf 0
#pragma unroll
    for (int i = 0; i < 4; i++) {
      int s = ((i * 4 + w) << 6) + lane;
      int rowK = s >> 4, cK = s & 15;
      gload_lds16(kp + (size_t)rowK * D_ + ((cK ^ (rowK & 7)) << 3), Kb + s * 8);
      int rowV = s >> 3, cV = s & 7;
      gload_lds16(vtp + (size_t)rowV * S_ + ((cV ^ (rowV & 7)) << 3), Vb + s * 8);
    }
    __syncthreads();

    int cur = 0;
    for (int nt = 0; nt <= last; nt++) {
      const int n0 = nt * 64;
      // issue next tile's loads into the other buffer (overlap whole iter)
      if (nt + 1 <= last) {
        const int n1 = n0 + 64;
        const int nb = (cur ^ 1) * 8192;
#pragma unroll
        for (int i = 0; i < 4; i++) {
          int s = ((i * 4 + w) << 6) + lane;
          int rowK = s >> 4, cK = s & 15;
          gload_lds16(kp + (size_t)(n1 + rowK) * D_ + ((cK ^ (rowK & 7)) << 3), Kb + nb + s * 8);
          int rowV = s >> 3, cV = s & 7;
          gload_lds16(vtp + (size_t)rowV * S_ + n1 + ((cV ^ (rowV & 7)) << 3), Vb + nb + s * 8);
        }
      }
      u16* Kc = Kb + cur * 8192;
      u16* Vc = Vb + cur * 8192;

      // ---- QK^T (contraction over D=128) ----
      f32x4 sacc[2][4];
#pragma unroll
      for (int mi = 0; mi < 2; mi++)
#pragma unroll
        for (int j = 0; j < 4; j++) sacc[mi][j] = zz;
#pragma unroll
      for (int kc = 0; kc < 4; kc++) {
        bf16x8 bk[4];
#pragma unroll
        for (int j = 0; j < 4; j++) {
          int row = j * 16 + lc;
          bk[j] = *reinterpret_cast<const bf16x8*>(
              Kc + row * 128 + ((((kc << 2) + hi) ^ (row & 7)) << 3));
        }
        __builtin_amdgcn_s_setprio(1);
#pragma unroll
        for (int mi = 0; mi < 2; mi++)
#pragma unroll
          for (int j = 0; j < 4; j++)
            sacc[mi][j] = __builtin_amdgcn_mfma_f32_16x16x32_bf16(aq[mi][kc], bk[j], sacc[mi][j], 0, 0, 0);
        __builtin_amdgcn_s_setprio(0);
      }
      bar_lds();  // all K reads done; Kc becomes P

      // ---- softmax (online, defer-max THR=8) ----
      const bool masked = (nt >= 2 * qt);
#pragma unroll
      for (int mi = 0; mi < 2; mi++)
#pragma unroll
        for (int r = 0; r < 4; r++) {
          const int mrow = w * 32 + mi * 16 + lr4 + r;  // local q row
          float svv[4];
          float t = -1e30f;
#pragma unroll
          for (int j = 0; j < 4; j++) {
            float sv = sacc[mi][j][r] * scale;
            if (masked && (n0 + j * 16 + lc > q0 + mrow)) sv = -1e30f;
            svv[j] = sv;
            t = fmaxf(t, sv);
          }
          t = fmaxf(t, __shfl_xor(t, 1));
          t = fmaxf(t, __shfl_xor(t, 2));
          t = fmaxf(t, __shfl_xor(t, 4));
          t = fmaxf(t, __shfl_xor(t, 8));
          if (t > mrun[mi][r] + 8.f) {
            float alpha = __expf(mrun[mi][r] - t);
            mrun[mi][r] = t;
            lrun[mi][r] *= alpha;
#pragma unroll
            for (int dj = 0; dj < 8; dj++) oacc[mi][dj][r] *= alpha;
          }
          const float mn = mrun[mi][r];
          float rs = 0.f;
#pragma unroll
          for (int j = 0; j < 4; j++) {
            float p = __expf(svv[j] - mn);
            rs += p;
            int c16 = j * 2 + (lc >> 3);
            Kc[mrow * 64 + ((c16 ^ (mrow & 7)) << 3) + (lc & 7)] = f2b(p);
          }
          rs += __shfl_xor(rs, 1);
          rs += __shfl_xor(rs, 2);
          rs += __shfl_xor(rs, 4);
          rs += __shfl_xor(rs, 8);
          lrun[mi][r] += rs;
        }
      bar_lds();  // P visible

      // ---- PV (contraction over kv=64) ----
#pragma unroll
      for (int kc = 0; kc < 2; kc++) {
        bf16x8 ap[2];
#pragma unroll
        for (int mi = 0; mi < 2; mi++) {
          int row = w * 32 + mi * 16 + lc;
          ap[mi] = *reinterpret_cast<const bf16x8*>(
              Kc + row * 64 + ((((kc << 2) + hi) ^ (row & 7)) << 3));
        }
        bf16x8 bv[8];
#pragma unroll
        for (int dj = 0; dj < 8; dj++) {
          int row = dj * 16 + lc;
          bv[dj] = *reinterpret_cast<const bf16x8*>(
              Vc + row * 64 + ((((kc << 2) + hi) ^ (row & 7)) << 3));
        }
        __builtin_amdgcn_s_setprio(1);
#pragma unroll
        for (int mi = 0; mi < 2; mi++)
#pragma unroll
          for (int dj = 0; dj < 8; dj++)
            oacc[mi][dj] = __builtin_amdgcn_mfma_f32_16x16x32_bf16(ap[mi], bv[dj], oacc[mi][dj], 0, 0, 0);
        __builtin_amdgcn_s_setprio(0);
      }
      __syncthreads();  // PV reads done + next tile's loads drained
      cur ^= 1;
    }

#pragma unroll
    for (int mi = 0; mi < 2; mi++)
#pragma unroll
      for (int dj = 0; dj < 8; dj++)
#pragma unroll
        for (int r = 0; r < 4; r++) {
          int sg = q0 + w * 32 + mi * 16 + lr4 + r;
          int d = dj * 16 + lc;
          float o = oacc[mi][dj][r] / lrun[mi][r];
          out[((size_t)b * S_ + sg) * NQ_ + h * D_ + d] = f2b(o);
        }
  }
}

extern "C" void kernel_launch(void* const* d_in, const int* in_sizes, int n_in,
                              void* d_out, int out_size, void* d_ws, size_t ws_size,
                              hipStream_t stream) {
  const float* hidden = (const float*)d_in[0];
  const float* cosp   = (const float*)d_in[1];
  const float* sinp   = (const float*)d_in[2];
  const float* q_w    = (const float*)d_in[3];
  const float* k_w    = (const float*)d_in[4];
  const float* v_w    = (const float*)d_in[5];
  const float* o_w    = (const float*)d_in[6];
  const float* qnw    = (const float*)d_in[7];
  const float* knw    = (const float*)d_in[8];

  char* p = (char*)d_ws;
  u16* hb  = (u16*)p; p += (size_t)M_ * HID_ * 2;
  u16* qwt = (u16*)p; p += (size_t)NQ_ * HID_ * 2;
  u16* kwt = (u16*)p; p += (size_t)NKV_ * HID_ * 2;
  u16* vwt = (u16*)p; p += (size_t)NKV_ * HID_ * 2;
  u16* owt = (u16*)p; p += (size_t)HID_ * NQ_ * 2;
  u16* qb  = (u16*)p; p += (size_t)B_ * H_ * S_ * D_ * 2;
  u16* kb  = (u16*)p; p += (size_t)B_ * KVH_ * S_ * D_ * 2;
  u16* vb  = (u16*)p; p += (size_t)B_ * KVH_ * S_ * D_ * 2;  // V^T [B][KVH][D][S]
  u16* ab  = (u16*)p; p += (size_t)M_ * NQ_ * 2;

  k_cvt<<<2048, 256, 0, stream>>>(hidden, hb, M_ * HID_ / 4);
  k_transpose<<<dim3(NQ_ / 64, HID_ / 64), 256, 0, stream>>>(q_w, qwt, HID_, NQ_);
  k_transpose<<<dim3(NKV_ / 64, HID_ / 64), 256, 0, stream>>>(k_w, kwt, HID_, NKV_);
  k_transpose<<<dim3(NKV_ / 64, HID_ / 64), 256, 0, stream>>>(v_w, vwt, HID_, NKV_);
  k_transpose<<<dim3(HID_ / 64, NQ_ / 64), 256, 0, stream>>>(o_w, owt, NQ_, HID_);
  k_gemm_qkv<<<dim3(M_ / 128, 40), 256, 0, stream>>>(hb, qwt, kwt, vwt, qb, kb, vb);
  k_norm_rope<<<(B_ * H_ * S_ + B_ * KVH_ * S_) / 4, 256, 0, stream>>>(qb, kb, cosp, sinp, qnw, knw);
  k_attn<<<dim3(8, B_ * H_), 256, 0, stream>>>(qb, kb, vb, ab);
  k_gemm_o<<<dim3(M_ / 128, HID_ / 128), 256, 0, stream>>>(ab, owt, (float*)d_out);
}

// Round 4
// 371.839 us; speedup vs baseline: 2.6384x; 1.1291x over previous
//
#include <hip/hip_runtime.h>
#include <hip/hip_bf16.h>

typedef unsigned short u16;
typedef __attribute__((ext_vector_type(4))) float f32x4;
typedef __attribute__((ext_vector_type(16))) float f32x16;
typedef __attribute__((ext_vector_type(8))) short bf16x8;
typedef __attribute__((ext_vector_type(4))) unsigned u32x4;

#define B_ 2
#define S_ 2048
#define HID_ 2048
#define H_ 32
#define KVH_ 4
#define D_ 128
#define M_ 4096
#define NQ_ 4096
#define NKV_ 512

typedef const __attribute__((address_space(1))) void gconst_void;
typedef __attribute__((address_space(3))) void lds_void;

static __device__ __forceinline__ void gload_lds16(const void* g, void* l) {
  __builtin_amdgcn_global_load_lds((gconst_void*)g, (lds_void*)l, 16, 0, 0);
}

static __device__ __forceinline__ u16 f2b(float f) {
  union { float f; unsigned i; } x; x.f = f;
  return (u16)((x.i + 0x7fffu + ((x.i >> 16) & 1u)) >> 16);
}
static __device__ __forceinline__ float b2f(u16 u) {
  union { unsigned i; float f; } x; x.i = ((unsigned)u) << 16;
  return x.f;
}

// ---------------- fp32 -> bf16 elementwise ----------------
__global__ void k_cvt(const float* __restrict__ in, u16* __restrict__ out, int n4) {
  int i = blockIdx.x * blockDim.x + threadIdx.x;
  int stride = gridDim.x * blockDim.x;
  for (; i < n4; i += stride) {
    float4 v = reinterpret_cast<const float4*>(in)[i];
    ushort4 o;
    o.x = f2b(v.x); o.y = f2b(v.y); o.z = f2b(v.z); o.w = f2b(v.w);
    reinterpret_cast<ushort4*>(out)[i] = o;
  }
}

// ---------------- W fp32 [K][N] -> Wt bf16 [N][K] ----------------
__global__ __launch_bounds__(256) void k_transpose(const float* __restrict__ W,
                                                   u16* __restrict__ Wt, int K, int N) {
  __shared__ u16 t[64][72];
  int n0 = blockIdx.x * 64, k0 = blockIdx.y * 64;
  int tid = threadIdx.x;
  int r = tid >> 4;
  int c4 = (tid & 15) * 4;
#pragma unroll
  for (int i = 0; i < 4; i++) {
    int k = r + i * 16;
    float4 v = *reinterpret_cast<const float4*>(W + (size_t)(k0 + k) * N + n0 + c4);
    t[k][c4 + 0] = f2b(v.x); t[k][c4 + 1] = f2b(v.y);
    t[k][c4 + 2] = f2b(v.z); t[k][c4 + 3] = f2b(v.w);
  }
  __syncthreads();
#pragma unroll
  for (int i = 0; i < 4; i++) {
    int n = r + i * 16;
    ushort4 o;
    o.x = t[c4 + 0][n]; o.y = t[c4 + 1][n]; o.z = t[c4 + 2][n]; o.w = t[c4 + 3][n];
    *reinterpret_cast<ushort4*>(Wt + (size_t)(n0 + n) * K + k0 + c4) = o;
  }
}

// ---- 128x128 bf16 GEMM core, 2-phase dbuf + swizzled global_load_lds staging ----
__device__ __forceinline__ void gemm_core(const u16* __restrict__ A, const u16* __restrict__ Bt,
                                          int K, int m0, int n0,
                                          u16* As, u16* Bs, f32x4 (&acc)[4][4]) {
  const int tid = threadIdx.x;
  const int lane = tid & 63;
  const int wid = tid >> 6;
  const int wr = wid >> 1, wc = wid & 1;
  const int lrow = lane & 15;
  const int hi = lane >> 4;
  const f32x4 zz = {0.f, 0.f, 0.f, 0.f};
#pragma unroll
  for (int i = 0; i < 4; i++)
#pragma unroll
    for (int j = 0; j < 4; j++) acc[i][j] = zz;

  const int srow = tid >> 3;
  const int sc16 = tid & 7;
  const int nk = K >> 6;
  int cur = 0;

#pragma unroll
  for (int rep = 0; rep < 4; rep++) {
    int row = rep * 32 + srow;
    int gcol = ((sc16 ^ (row & 7)) << 3);
    gload_lds16(A + (size_t)(m0 + row) * K + gcol, As + row * 64 + sc16 * 8);
    gload_lds16(Bt + (size_t)(n0 + row) * K + gcol, Bs + row * 64 + sc16 * 8);
  }
  __syncthreads();

  for (int t = 0; t < nk; t++) {
    if (t + 1 < nk) {
      int nxt = cur ^ 1;
      int kb = (t + 1) << 6;
#pragma unroll
      for (int rep = 0; rep < 4; rep++) {
        int row = rep * 32 + srow;
        int gcol = kb + ((sc16 ^ (row & 7)) << 3);
        gload_lds16(A + (size_t)(m0 + row) * K + gcol, As + nxt * 8192 + row * 64 + sc16 * 8);
        gload_lds16(Bt + (size_t)(n0 + row) * K + gcol, Bs + nxt * 8192 + row * 64 + sc16 * 8);
      }
    }
    const u16* Ac = As + cur * 8192;
    const u16* Bc = Bs + cur * 8192;
#pragma unroll
    for (int kc = 0; kc < 2; kc++) {
      bf16x8 af[4], bfr[4];
#pragma unroll
      for (int i = 0; i < 4; i++) {
        int row = wr * 64 + i * 16 + lrow;
        af[i] = *reinterpret_cast<const bf16x8*>(Ac + row * 64 + ((((kc << 2) + hi) ^ (row & 7)) << 3));
      }
#pragma unroll
      for (int j = 0; j < 4; j++) {
        int row = wc * 64 + j * 16 + lrow;
        bfr[j] = *reinterpret_cast<const bf16x8*>(Bc + row * 64 + ((((kc << 2) + hi) ^ (row & 7)) << 3));
      }
#pragma unroll
      for (int i = 0; i < 4; i++)
#pragma unroll
        for (int j = 0; j < 4; j++)
          acc[i][j] = __builtin_amdgcn_mfma_f32_16x16x32_bf16(af[i], bfr[j], acc[i][j], 0, 0, 0);
    }
    __syncthreads();
    cur ^= 1;
  }
}

// ---------------- QKV projection (V written transposed [B][KVH][D][S]) ----------------
__global__ __launch_bounds__(256, 2) void k_gemm_qkv(const u16* __restrict__ hb,
    const u16* __restrict__ qwt, const u16* __restrict__ kwt, const u16* __restrict__ vwt,
    u16* __restrict__ qb, u16* __restrict__ kb, u16* __restrict__ vb) {
  __shared__ u16 As[2 * 128 * 64], Bs[2 * 128 * 64];
  int mt = blockIdx.x, nt = blockIdx.y;
  const u16* Bt;
  if (nt < 32)      Bt = qwt;
  else if (nt < 36) Bt = kwt;
  else              Bt = vwt;
  int head = (nt < 32) ? nt : ((nt < 36) ? nt - 32 : nt - 36);
  f32x4 acc[4][4];
  gemm_core(hb, Bt, HID_, mt * 128, head * 128, As, Bs, acc);
  const int lane = threadIdx.x & 63;
  const int wid = threadIdx.x >> 6;
  const int wr = wid >> 1, wc = wid & 1;
  const int lr4 = (lane >> 4) * 4, lc = lane & 15;
#pragma unroll
  for (int i = 0; i < 4; i++)
#pragma unroll
    for (int j = 0; j < 4; j++)
#pragma unroll
      for (int r = 0; r < 4; r++) {
        int m = mt * 128 + wr * 64 + i * 16 + lr4 + r;
        int d = wc * 64 + j * 16 + lc;
        int b = m >> 11, s = m & (S_ - 1);
        u16 val = f2b(acc[i][j][r]);
        if (nt < 32) {
          qb[(((size_t)b * H_ + head) * S_ + s) * D_ + d] = val;
        } else if (nt < 36) {
          kb[(((size_t)b * KVH_ + head) * S_ + s) * D_ + d] = val;
        } else {
          vb[(((size_t)b * KVH_ + head) * D_ + d) * S_ + s] = val;  // transposed
        }
      }
}

// ---------------- O projection ----------------
__global__ __launch_bounds__(256, 2) void k_gemm_o(const u16* __restrict__ ab,
    const u16* __restrict__ owt, float* __restrict__ out) {
  __shared__ u16 As[2 * 128 * 64], Bs[2 * 128 * 64];
  int mt = blockIdx.x, nt = blockIdx.y;
  f32x4 acc[4][4];
  gemm_core(ab, owt, NQ_, mt * 128, nt * 128, As, Bs, acc);
  const int lane = threadIdx.x & 63;
  const int wid = threadIdx.x >> 6;
  const int wr = wid >> 1, wc = wid & 1;
  const int lr4 = (lane >> 4) * 4, lc = lane & 15;
#pragma unroll
  for (int i = 0; i < 4; i++)
#pragma unroll
    for (int j = 0; j < 4; j++)
#pragma unroll
      for (int r = 0; r < 4; r++) {
        int m = mt * 128 + wr * 64 + i * 16 + lr4 + r;
        int n = nt * 128 + wc * 64 + j * 16 + lc;
        out[(size_t)m * HID_ + n] = acc[i][j][r];
      }
}

// ---------------- RMSNorm + RoPE (in place on q/k) ----------------
__global__ __launch_bounds__(256) void k_norm_rope(u16* __restrict__ qb, u16* __restrict__ kb,
    const float* __restrict__ cosp, const float* __restrict__ sinp,
    const float* __restrict__ qnw, const float* __restrict__ knw) {
  int row = blockIdx.x * 4 + (threadIdx.x >> 6);
  int lane = threadIdx.x & 63;
  const int QROWS = B_ * H_ * S_;
  u16* ptr; const float* nw; int b, s;
  if (row < QROWS) {
    ptr = qb + (size_t)row * D_; nw = qnw;
    s = row & (S_ - 1); b = row / (H_ * S_);
  } else {
    int r2 = row - QROWS;
    ptr = kb + (size_t)r2 * D_; nw = knw;
    s = r2 & (S_ - 1); b = r2 / (KVH_ * S_);
  }
  int d = lane * 2;
  float x0 = b2f(ptr[d]), x1 = b2f(ptr[d + 1]);
  float ss = x0 * x0 + x1 * x1;
#pragma unroll
  for (int m = 1; m < 64; m <<= 1) ss += __shfl_xor(ss, m);
  float inv = rsqrtf(ss * (1.0f / 128.0f) + 1e-6f);
  x0 = x0 * inv * nw[d]; x1 = x1 * inv * nw[d + 1];
  float p0 = __shfl_xor(x0, 32), p1 = __shfl_xor(x1, 32);
  float r0 = (lane < 32) ? -p0 : p0;
  float r1 = (lane < 32) ? -p1 : p1;
  const float* cp = cosp + ((size_t)b * S_ + s) * D_;
  const float* sp = sinp + ((size_t)b * S_ + s) * D_;
  ptr[d]     = f2b(x0 * cp[d]     + r0 * sp[d]);
  ptr[d + 1] = f2b(x1 * cp[d + 1] + r1 * sp[d + 1]);
}

// ---------------- causal GQA flash attention (8-warp, 32x32, swapped QK^T) -----
// grid (4, B*H), 512 threads. Block x does q-tiles {x, 7-x} of 256 rows: 36 kv-iters.
// Warp w owns q rows [q0+32w, q0+32w+32). KVBLK=64, dbuf LDS, 1 barrier/tile.
// Swapped QK^T: S^T = mfma(K, Q) -> lane holds P[q=lane&31][32 kv values].
// Softmax in exp2 domain, fully in-register; P->PV A-frags via cvt_pk+permlane32_swap.
__global__ __launch_bounds__(512, 2) void k_attn(const u16* __restrict__ q,
    const u16* __restrict__ k, const u16* __restrict__ vt, u16* __restrict__ out) {
  __shared__ u16 Kb[2 * 64 * 128];   // [kv 64][d 128], 16 slots/row, slot ^= row&15
  __shared__ u16 Vb[2 * 128 * 64];   // [d 128][kv 64],  8 slots/row, slot ^= row&7
  const int bh = blockIdx.y;
  const int b = bh >> 5, h = bh & 31;
  const int kvh = h >> 3;
  const int tid = threadIdx.x, lane = tid & 63, w = tid >> 6;
  const int lq = lane & 31, hi = lane >> 5;
  const u16* qp  = q  + ((size_t)(b * H_ + h) * S_) * D_;
  const u16* kp  = k  + ((size_t)(b * KVH_ + kvh) * S_) * D_;
  const u16* vtp = vt + ((size_t)(b * KVH_ + kvh) * D_) * S_;

  // staging constants (per-thread)
  const int rowKa = tid >> 4;                       // 0..31 (pass2: +32)
  const int colK  = ((tid & 15) ^ (rowKa & 15)) << 3;
  const int rowVa = tid >> 3;                       // 0..63 (pass2: +64)
  const int colV  = ((tid & 7) ^ (rowVa & 7)) << 3;

  const float KSC = 0.08838834764831845f * 1.44269504088896340f;  // scale*log2e
  const f32x16 z16 = {0.f};

  int cur = 0;
  for (int half = 0; half < 2; half++) {
    const int qt = half ? (7 - (int)blockIdx.x) : (int)blockIdx.x;
    const int q0 = qt * 256;
    const int last = 4 * qt + 3;
    const int qg = q0 + 32 * w + lq;  // this lane's q row (its P column)

    // stage kv-tile 0 into buf `cur`
    {
      u16* kd = Kb + cur * 8192 + tid * 8;
      u16* vd = Vb + cur * 8192 + tid * 8;
      gload_lds16(kp + (size_t)rowKa * D_ + colK, kd);
      gload_lds16(kp + (size_t)(rowKa + 32) * D_ + colK, kd + 4096);
      gload_lds16(vtp + (size_t)rowVa * S_ + colV, vd);
      gload_lds16(vtp + (size_t)(rowVa + 64) * S_ + colV, vd + 4096);
    }

    // Q fragments (B-operand): qf[ds] = Q[qg][16ds + 8hi + e]
    bf16x8 qf[8];
#pragma unroll
    for (int ds = 0; ds < 8; ds++)
      qf[ds] = *reinterpret_cast<const bf16x8*>(qp + (size_t)qg * D_ + ds * 16 + hi * 8);

    f32x16 oacc[4];
#pragma unroll
    for (int dt = 0; dt < 4; dt++) oacc[dt] = z16;
    float mrun = -1e30f, lrun = 0.f;

    __syncthreads();

    for (int nt = 0; nt <= last; nt++) {
      const int n0 = nt * 64;
      if (nt < last) {
        const int n1 = n0 + 64;
        u16* kd = Kb + (cur ^ 1) * 8192 + tid * 8;
        u16* vd = Vb + (cur ^ 1) * 8192 + tid * 8;
        gload_lds16(kp + (size_t)(n1 + rowKa) * D_ + colK, kd);
        gload_lds16(kp + (size_t)(n1 + rowKa + 32) * D_ + colK, kd + 4096);
        gload_lds16(vtp + (size_t)rowVa * S_ + n1 + colV, vd);
        gload_lds16(vtp + (size_t)(rowVa + 64) * S_ + n1 + colV, vd + 4096);
      }
      const u16* Kc = Kb + cur * 8192;
      const u16* Vc = Vb + cur * 8192;

      const bool skip = (n0 > q0 + 32 * w + 31);
      if (!skip) {
        const bool needmask = (n0 + 63 > q0 + 32 * w);

        // ---- QK^T: S^T[kv][q] = mfma(A=K, B=Q) over 8 d-steps ----
        f32x16 sacc[2];
        sacc[0] = z16; sacc[1] = z16;
#pragma unroll
        for (int ds = 0; ds < 8; ds++) {
          const int sl = (((ds << 1) + hi) ^ (lq & 15)) << 3;
          bf16x8 ka0 = *reinterpret_cast<const bf16x8*>(Kc + lq * 128 + sl);
          bf16x8 ka1 = *reinterpret_cast<const bf16x8*>(Kc + (lq + 32) * 128 + sl);
          __builtin_amdgcn_s_setprio(1);
          sacc[0] = __builtin_amdgcn_mfma_f32_32x32x16_bf16(ka0, qf[ds], sacc[0], 0, 0, 0);
          sacc[1] = __builtin_amdgcn_mfma_f32_32x32x16_bf16(ka1, qf[ds], sacc[1], 0, 0, 0);
          __builtin_amdgcn_s_setprio(0);
        }

        // ---- softmax, exp2 domain, in-register ----
        float tm = -1e30f;
#pragma unroll
        for (int t = 0; t < 2; t++)
#pragma unroll
          for (int r = 0; r < 16; r++) {
            float s2 = sacc[t][r] * KSC;
            if (needmask) {
              int kvg = n0 + 32 * t + (r & 3) + 8 * (r >> 2) + 4 * hi;
              if (kvg > qg) s2 = -1e30f;
            }
            sacc[t][r] = s2;
            tm = fmaxf(tm, s2);
          }
        tm = fmaxf(tm, __shfl_xor(tm, 32));
        if (__any(tm > mrun + 8.f)) {   // defer-max (T13), log2 units
          float mn = fmaxf(mrun, tm);
          float al = exp2f(mrun - mn);
          mrun = mn;
          lrun *= al;
#pragma unroll
          for (int r = 0; r < 16; r++) {
            float ar = __shfl(al, (r & 3) + 8 * (r >> 2) + 4 * hi);
#pragma unroll
            for (int dt = 0; dt < 4; dt++) oacc[dt][r] *= ar;
          }
        }
        float rs = 0.f;
#pragma unroll
        for (int t = 0; t < 2; t++)
#pragma unroll
          for (int r = 0; r < 16; r++) {
            float pv = exp2f(sacc[t][r] - mrun);
            sacc[t][r] = pv;
            rs += pv;
          }
        rs += __shfl_xor(rs, 32);
        lrun += rs;

        // ---- P -> bf16 A-frags: cvt_pk + permlane32_swap (T12) ----
        u32x4 pa[4];
#pragma unroll
        for (int t = 0; t < 2; t++)
#pragma unroll
          for (int ksl = 0; ksl < 2; ksl++) {
            unsigned wa, wb, wc2, wd;
            asm("v_cvt_pk_bf16_f32 %0, %1, %2" : "=v"(wa)
                : "v"(sacc[t][8 * ksl + 0]), "v"(sacc[t][8 * ksl + 1]));
            asm("v_cvt_pk_bf16_f32 %0, %1, %2" : "=v"(wb)
                : "v"(sacc[t][8 * ksl + 2]), "v"(sacc[t][8 * ksl + 3]));
            asm("v_cvt_pk_bf16_f32 %0, %1, %2" : "=v"(wc2)
                : "v"(sacc[t][8 * ksl + 4]), "v"(sacc[t][8 * ksl + 5]));
            asm("v_cvt_pk_bf16_f32 %0, %1, %2" : "=v"(wd)
                : "v"(sacc[t][8 * ksl + 6]), "v"(sacc[t][8 * ksl + 7]));
            asm("v_permlane32_swap_b32 %0, %1" : "+v"(wa), "+v"(wc2));
            asm("v_permlane32_swap_b32 %0, %1" : "+v"(wb), "+v"(wd));
            u32x4 t4 = {wa, wb, wc2, wd};
            pa[t * 2 + ksl] = t4;
          }

        // ---- PV: O[q][d] += P * V, 4 k-steps x 4 d-tiles ----
#pragma unroll
        for (int ks = 0; ks < 4; ks++) {
          bf16x8 paf = __builtin_bit_cast(bf16x8, pa[ks]);
          bf16x8 bv[4];
#pragma unroll
          for (int dt = 0; dt < 4; dt++) {
            int rowv = dt * 32 + lq;
            bv[dt] = *reinterpret_cast<const bf16x8*>(
                Vc + rowv * 64 + ((((ks << 1) + hi) ^ (rowv & 7)) << 3));
          }
          __builtin_amdgcn_s_setprio(1);
#pragma unroll
          for (int dt = 0; dt < 4; dt++)
            oacc[dt] = __builtin_amdgcn_mfma_f32_32x32x16_bf16(paf, bv[dt], oacc[dt], 0, 0, 0);
          __builtin_amdgcn_s_setprio(0);
        }
      }
      __syncthreads();  // LDS reads done + next tile's staged loads landed
      cur ^= 1;
    }

    // ---- epilogue: O[q][d] / l[q] ----
    float linv = 1.0f / lrun;
#pragma unroll
    for (int r = 0; r < 16; r++) {
      const int idx_r = (r & 3) + 8 * (r >> 2) + 4 * hi;
      float lr = __shfl(linv, idx_r);
      size_t base = ((size_t)b * S_ + (q0 + 32 * w + idx_r)) * NQ_ + h * D_ + lq;
#pragma unroll
      for (int dt = 0; dt < 4; dt++)
        out[base + dt * 32] = f2b(oacc[dt][r] * lr);
    }
  }
}

extern "C" void kernel_launch(void* const* d_in, const int* in_sizes, int n_in,
                              void* d_out, int out_size, void* d_ws, size_t ws_size,
                              hipStream_t stream) {
  const float* hidden = (const float*)d_in[0];
  const float* cosp   = (const float*)d_in[1];
  const float* sinp   = (const float*)d_in[2];
  const float* q_w    = (const float*)d_in[3];
  const float* k_w    = (const float*)d_in[4];
  const float* v_w    = (const float*)d_in[5];
  const float* o_w    = (const float*)d_in[6];
  const float* qnw    = (const float*)d_in[7];
  const float* knw    = (const float*)d_in[8];

  char* p = (char*)d_ws;
  u16* hb  = (u16*)p; p += (size_t)M_ * HID_ * 2;
  u16* qwt = (u16*)p; p += (size_t)NQ_ * HID_ * 2;
  u16* kwt = (u16*)p; p += (size_t)NKV_ * HID_ * 2;
  u16* vwt = (u16*)p; p += (size_t)NKV_ * HID_ * 2;
  u16* owt = (u16*)p; p += (size_t)HID_ * NQ_ * 2;
  u16* qb  = (u16*)p; p += (size_t)B_ * H_ * S_ * D_ * 2;
  u16* kb  = (u16*)p; p += (size_t)B_ * KVH_ * S_ * D_ * 2;
  u16* vb  = (u16*)p; p += (size_t)B_ * KVH_ * S_ * D_ * 2;  // V^T [B][KVH][D][S]
  u16* ab  = (u16*)p; p += (size_t)M_ * NQ_ * 2;

  k_cvt<<<2048, 256, 0, stream>>>(hidden, hb, M_ * HID_ / 4);
  k_transpose<<<dim3(NQ_ / 64, HID_ / 64), 256, 0, stream>>>(q_w, qwt, HID_, NQ_);
  k_transpose<<<dim3(NKV_ / 64, HID_ / 64), 256, 0, stream>>>(k_w, kwt, HID_, NKV_);
  k_transpose<<<dim3(NKV_ / 64, HID_ / 64), 256, 0, stream>>>(v_w, vwt, HID_, NKV_);
  k_transpose<<<dim3(HID_ / 64, NQ_ / 64), 256, 0, stream>>>(o_w, owt, NQ_, HID_);
  k_gemm_qkv<<<dim3(M_ / 128, 40), 256, 0, stream>>>(hb, qwt, kwt, vwt, qb, kb, vb);
  k_norm_rope<<<(B_ * H_ * S_ + B_ * KVH_ * S_) / 4, 256, 0, stream>>>(qb, kb, cosp, sinp, qnw, knw);
  k_attn<<<dim3(4, B_ * H_), 512, 0, stream>>>(qb, kb, vb, ab);
  k_gemm_o<<<dim3(M_ / 128, HID_ / 128), 256, 0, stream>>>(ab, owt, (float*)d_out);
}

// Round 5
// 361.215 us; speedup vs baseline: 2.7160x; 1.0294x over previous
//
#include <hip/hip_runtime.h>
#include <hip/hip_bf16.h>

typedef unsigned short u16;
typedef __attribute__((ext_vector_type(4))) float f32x4;
typedef __attribute__((ext_vector_type(16))) float f32x16;
typedef __attribute__((ext_vector_type(8))) short bf16x8;
typedef __attribute__((ext_vector_type(4))) unsigned u32x4;

#define B_ 2
#define S_ 2048
#define HID_ 2048
#define H_ 32
#define KVH_ 4
#define D_ 128
#define M_ 4096
#define NQ_ 4096
#define NKV_ 512

typedef const __attribute__((address_space(1))) void gconst_void;
typedef __attribute__((address_space(3))) void lds_void;

static __device__ __forceinline__ void gload_lds16(const void* g, void* l) {
  __builtin_amdgcn_global_load_lds((gconst_void*)g, (lds_void*)l, 16, 0, 0);
}

#define WAITV(N) asm volatile("s_waitcnt vmcnt(" #N ")" ::: "memory")
#define WAITL0() asm volatile("s_waitcnt lgkmcnt(0)" ::: "memory")

static __device__ __forceinline__ u16 f2b(float f) {
  union { float f; unsigned i; } x; x.f = f;
  return (u16)((x.i + 0x7fffu + ((x.i >> 16) & 1u)) >> 16);
}
static __device__ __forceinline__ float b2f(u16 u) {
  union { unsigned i; float f; } x; x.i = ((unsigned)u) << 16;
  return x.f;
}

// ---------------- fp32 -> bf16 elementwise ----------------
__global__ void k_cvt(const float* __restrict__ in, u16* __restrict__ out, int n4) {
  int i = blockIdx.x * blockDim.x + threadIdx.x;
  int stride = gridDim.x * blockDim.x;
  for (; i < n4; i += stride) {
    float4 v = reinterpret_cast<const float4*>(in)[i];
    ushort4 o;
    o.x = f2b(v.x); o.y = f2b(v.y); o.z = f2b(v.z); o.w = f2b(v.w);
    reinterpret_cast<ushort4*>(out)[i] = o;
  }
}

// ---------------- W fp32 [K][N] -> Wt bf16 [N][K] ----------------
__global__ __launch_bounds__(256) void k_transpose(const float* __restrict__ W,
                                                   u16* __restrict__ Wt, int K, int N) {
  __shared__ u16 t[64][72];
  int n0 = blockIdx.x * 64, k0 = blockIdx.y * 64;
  int tid = threadIdx.x;
  int r = tid >> 4;
  int c4 = (tid & 15) * 4;
#pragma unroll
  for (int i = 0; i < 4; i++) {
    int k = r + i * 16;
    float4 v = *reinterpret_cast<const float4*>(W + (size_t)(k0 + k) * N + n0 + c4);
    t[k][c4 + 0] = f2b(v.x); t[k][c4 + 1] = f2b(v.y);
    t[k][c4 + 2] = f2b(v.z); t[k][c4 + 3] = f2b(v.w);
  }
  __syncthreads();
#pragma unroll
  for (int i = 0; i < 4; i++) {
    int n = r + i * 16;
    ushort4 o;
    o.x = t[c4 + 0][n]; o.y = t[c4 + 1][n]; o.z = t[c4 + 2][n]; o.w = t[c4 + 3][n];
    *reinterpret_cast<ushort4*>(Wt + (size_t)(n0 + n) * K + k0 + c4) = o;
  }
}

// ---- 128x128 bf16 GEMM core, 2-phase dbuf + swizzled global_load_lds staging ----
__device__ __forceinline__ void gemm_core(const u16* __restrict__ A, const u16* __restrict__ Bt,
                                          int K, int m0, int n0,
                                          u16* As, u16* Bs, f32x4 (&acc)[4][4]) {
  const int tid = threadIdx.x;
  const int lane = tid & 63;
  const int wid = tid >> 6;
  const int wr = wid >> 1, wc = wid & 1;
  const int lrow = lane & 15;
  const int hi = lane >> 4;
  const f32x4 zz = {0.f, 0.f, 0.f, 0.f};
#pragma unroll
  for (int i = 0; i < 4; i++)
#pragma unroll
    for (int j = 0; j < 4; j++) acc[i][j] = zz;

  const int srow = tid >> 3;
  const int sc16 = tid & 7;
  const int nk = K >> 6;
  int cur = 0;

#pragma unroll
  for (int rep = 0; rep < 4; rep++) {
    int row = rep * 32 + srow;
    int gcol = ((sc16 ^ (row & 7)) << 3);
    gload_lds16(A + (size_t)(m0 + row) * K + gcol, As + row * 64 + sc16 * 8);
    gload_lds16(Bt + (size_t)(n0 + row) * K + gcol, Bs + row * 64 + sc16 * 8);
  }
  __syncthreads();

  for (int t = 0; t < nk; t++) {
    if (t + 1 < nk) {
      int nxt = cur ^ 1;
      int kb = (t + 1) << 6;
#pragma unroll
      for (int rep = 0; rep < 4; rep++) {
        int row = rep * 32 + srow;
        int gcol = kb + ((sc16 ^ (row & 7)) << 3);
        gload_lds16(A + (size_t)(m0 + row) * K + gcol, As + nxt * 8192 + row * 64 + sc16 * 8);
        gload_lds16(Bt + (size_t)(n0 + row) * K + gcol, Bs + nxt * 8192 + row * 64 + sc16 * 8);
      }
    }
    const u16* Ac = As + cur * 8192;
    const u16* Bc = Bs + cur * 8192;
#pragma unroll
    for (int kc = 0; kc < 2; kc++) {
      bf16x8 af[4], bfr[4];
#pragma unroll
      for (int i = 0; i < 4; i++) {
        int row = wr * 64 + i * 16 + lrow;
        af[i] = *reinterpret_cast<const bf16x8*>(Ac + row * 64 + ((((kc << 2) + hi) ^ (row & 7)) << 3));
      }
#pragma unroll
      for (int j = 0; j < 4; j++) {
        int row = wc * 64 + j * 16 + lrow;
        bfr[j] = *reinterpret_cast<const bf16x8*>(Bc + row * 64 + ((((kc << 2) + hi) ^ (row & 7)) << 3));
      }
#pragma unroll
      for (int i = 0; i < 4; i++)
#pragma unroll
        for (int j = 0; j < 4; j++)
          acc[i][j] = __builtin_amdgcn_mfma_f32_16x16x32_bf16(af[i], bfr[j], acc[i][j], 0, 0, 0);
    }
    __syncthreads();
    cur ^= 1;
  }
}

// ---------------- Q projection: 8-phase 256x256 template (T2+T3+T4+T5) ----------------
// grid 256 (1D, XCD-swizzled), 512 threads = 8 waves (2M x 4N), per-wave 128x64.
// BK=64; LDS = 2 dbuf x 2 halves x 128x64 x {A,B} = 128 KB. Gray-code quadrant phases.
__global__ __launch_bounds__(512, 2) void k_gemm_q8(const u16* __restrict__ A,
    const u16* __restrict__ Bt, u16* __restrict__ qb) {
  __shared__ u16 Ash[2][2][128 * 64];
  __shared__ u16 Bsh[2][2][128 * 64];
  const int bid = blockIdx.x;
  const int wg = (bid & 7) * 32 + (bid >> 3);   // chunked XCD swizzle (256 % 8 == 0)
  const int mt = wg & 15, nt = wg >> 4;
  const int m0 = mt * 256, n0 = nt * 256;
  const int K = HID_, nk = K >> 6;
  const int tid = threadIdx.x, lane = tid & 63;
  const int wv = tid >> 6, wr = wv >> 2, wc = wv & 3;
  const int lrow = lane & 15, hi4 = lane >> 4;

  // staging: per half-tile (128x64) 2 loads/thread; s = tid (+512)
  const int s0r = tid >> 3, sc = tid & 7;
  const int s1r = (tid + 512) >> 3;

  auto stgA = [&](int h, int t, int d) {
    gload_lds16(A + (size_t)(m0 + h * 128 + s0r) * K + t * 64 + ((sc ^ (s0r & 7)) << 3),
                &Ash[d][h][s0r * 64 + sc * 8]);
    gload_lds16(A + (size_t)(m0 + h * 128 + s1r) * K + t * 64 + ((sc ^ (s1r & 7)) << 3),
                &Ash[d][h][s1r * 64 + sc * 8]);
  };
  auto stgB = [&](int h, int t, int d) {
    gload_lds16(Bt + (size_t)(n0 + h * 128 + s0r) * K + t * 64 + ((sc ^ (s0r & 7)) << 3),
                &Bsh[d][h][s0r * 64 + sc * 8]);
    gload_lds16(Bt + (size_t)(n0 + h * 128 + s1r) * K + t * 64 + ((sc ^ (s1r & 7)) << 3),
                &Bsh[d][h][s1r * 64 + sc * 8]);
  };

  f32x4 acc[8][4];
  const f32x4 zz = {0.f, 0.f, 0.f, 0.f};
#pragma unroll
  for (int f = 0; f < 8; f++)
#pragma unroll
    for (int j = 0; j < 4; j++) acc[f][j] = zz;

  bf16x8 af[4][2], bfr[2][2];

  // A fragment f (0..7): global M row = f*32 + wr*16 + lrow -> half = f>>2, row-in-half = (f&3)*32+wr*16+lrow
  auto lda = [&](int mh, int d) {
#pragma unroll
    for (int fi = 0; fi < 4; fi++) {
      int row = fi * 32 + wr * 16 + lrow;
#pragma unroll
      for (int kk = 0; kk < 2; kk++)
        af[fi][kk] = *reinterpret_cast<const bf16x8*>(
            &Ash[d][mh][row * 64 + ((((kk << 2) + hi4) ^ (row & 7)) << 3)]);
    }
  };
  // B fragment j (0..3): global N row = j*64 + wc*16 + lrow -> half = j>>1, row-in-half = (j&1)*64+wc*16+lrow
  auto ldb = [&](int nh, int d) {
#pragma unroll
    for (int ji = 0; ji < 2; ji++) {
      int row = ji * 64 + wc * 16 + lrow;
#pragma unroll
      for (int kk = 0; kk < 2; kk++)
        bfr[ji][kk] = *reinterpret_cast<const bf16x8*>(
            &Bsh[d][nh][row * 64 + ((((kk << 2) + hi4) ^ (row & 7)) << 3)]);
    }
  };
  auto mq = [&](int mh, int nh) {
    __builtin_amdgcn_s_setprio(1);
#pragma unroll
    for (int kk = 0; kk < 2; kk++)
#pragma unroll
      for (int fi = 0; fi < 4; fi++)
#pragma unroll
        for (int ji = 0; ji < 2; ji++)
          acc[mh * 4 + fi][nh * 2 + ji] = __builtin_amdgcn_mfma_f32_16x16x32_bf16(
              af[fi][kk], bfr[ji][kk], acc[mh * 4 + fi][nh * 2 + ji], 0, 0, 0);
    __builtin_amdgcn_s_setprio(0);
  };

  // prologue: stage tile 0 fully, drain
  stgA(0, 0, 0); stgB(0, 0, 0); stgA(1, 0, 0); stgB(1, 0, 0);
  WAITV(0);
  __builtin_amdgcn_s_barrier();

  for (int t = 0; t < nk; t++) {
    const int d = t & 1, nd = d ^ 1;
    const bool pre = (t + 1 < nk);
    // phase 1: quadrant (0,0); stage Alo+Blo of t+1
    if (pre) { stgA(0, t + 1, nd); stgB(0, t + 1, nd); }
    lda(0, d); ldb(0, d);
    WAITV(6);
    __builtin_amdgcn_sched_barrier(0);
    __builtin_amdgcn_s_barrier();
    WAITL0();
    __builtin_amdgcn_sched_barrier(0);
    mq(0, 0);
    __builtin_amdgcn_s_barrier();
    // phase 2: quadrant (1,0); stage Ahi of t+1
    if (pre) stgA(1, t + 1, nd);
    lda(1, d);
    WAITV(6);
    __builtin_amdgcn_sched_barrier(0);
    __builtin_amdgcn_s_barrier();
    WAITL0();
    __builtin_amdgcn_sched_barrier(0);
    mq(1, 0);
    __builtin_amdgcn_s_barrier();
    // phase 3: quadrant (1,1); stage Bhi of t+1
    if (pre) stgB(1, t + 1, nd);
    ldb(1, d);
    __builtin_amdgcn_sched_barrier(0);
    __builtin_amdgcn_s_barrier();
    WAITL0();
    __builtin_amdgcn_sched_barrier(0);
    mq(1, 1);
    __builtin_amdgcn_s_barrier();
    // phase 4: quadrant (0,1); drain t+1's Alo+Blo for next iter's phase 1
    lda(0, d);
    WAITV(4);
    __builtin_amdgcn_sched_barrier(0);
    __builtin_amdgcn_s_barrier();
    WAITL0();
    __builtin_amdgcn_sched_barrier(0);
    mq(0, 1);
    __builtin_amdgcn_s_barrier();
  }

  // epilogue: scatter into qb [B][H][S][D]
  const int lr4 = hi4 * 4, lc = lane & 15;
#pragma unroll
  for (int f = 0; f < 8; f++)
#pragma unroll
    for (int j = 0; j < 4; j++)
#pragma unroll
      for (int rr = 0; rr < 4; rr++) {
        int m = m0 + f * 32 + wr * 16 + lr4 + rr;
        int ncol = n0 + j * 64 + wc * 16 + lc;
        int b = m >> 11, s = m & (S_ - 1);
        int head = ncol >> 7, dd = ncol & 127;
        qb[(((size_t)b * H_ + head) * S_ + s) * D_ + dd] = f2b(acc[f][j][rr]);
      }
}

// ---------------- K/V projections (128^2 core), grid 256 1D swizzled ----------------
__global__ __launch_bounds__(256, 2) void k_gemm_kv(const u16* __restrict__ hb,
    const u16* __restrict__ kwt, const u16* __restrict__ vwt,
    u16* __restrict__ kb, u16* __restrict__ vb) {
  __shared__ u16 As[2 * 128 * 64], Bs[2 * 128 * 64];
  const int bid = blockIdx.x;
  const int wg = (bid & 7) * 32 + (bid >> 3);
  const int mt = wg & 31, nt = wg >> 5;   // nt 0..7: K heads 0-3, V heads 0-3
  const bool isv = nt >= 4;
  const int head = isv ? nt - 4 : nt;
  const u16* Bt = isv ? vwt : kwt;
  f32x4 acc[4][4];
  gemm_core(hb, Bt, HID_, mt * 128, head * 128, As, Bs, acc);
  const int lane = threadIdx.x & 63;
  const int wid = threadIdx.x >> 6;
  const int wr = wid >> 1, wc = wid & 1;
  const int lr4 = (lane >> 4) * 4, lc = lane & 15;
#pragma unroll
  for (int i = 0; i < 4; i++)
#pragma unroll
    for (int j = 0; j < 4; j++)
#pragma unroll
      for (int r = 0; r < 4; r++) {
        int m = mt * 128 + wr * 64 + i * 16 + lr4 + r;
        int d = wc * 64 + j * 16 + lc;
        int b = m >> 11, s = m & (S_ - 1);
        u16 val = f2b(acc[i][j][r]);
        if (isv) vb[(((size_t)b * KVH_ + head) * D_ + d) * S_ + s] = val;  // transposed
        else     kb[(((size_t)b * KVH_ + head) * S_ + s) * D_ + d] = val;
      }
}

// ---------------- O projection (128^2 core), grid 512 1D swizzled ----------------
__global__ __launch_bounds__(256, 2) void k_gemm_o(const u16* __restrict__ ab,
    const u16* __restrict__ owt, float* __restrict__ out) {
  __shared__ u16 As[2 * 128 * 64], Bs[2 * 128 * 64];
  const int bid = blockIdx.x;
  const int wg = (bid & 7) * 64 + (bid >> 3);
  const int mt = wg & 31, nt = wg >> 5;
  f32x4 acc[4][4];
  gemm_core(ab, owt, NQ_, mt * 128, nt * 128, As, Bs, acc);
  const int lane = threadIdx.x & 63;
  const int wid = threadIdx.x >> 6;
  const int wr = wid >> 1, wc = wid & 1;
  const int lr4 = (lane >> 4) * 4, lc = lane & 15;
#pragma unroll
  for (int i = 0; i < 4; i++)
#pragma unroll
    for (int j = 0; j < 4; j++)
#pragma unroll
      for (int r = 0; r < 4; r++) {
        int m = mt * 128 + wr * 64 + i * 16 + lr4 + r;
        int n = nt * 128 + wc * 64 + j * 16 + lc;
        out[(size_t)m * HID_ + n] = acc[i][j][r];
      }
}

// ---------------- RMSNorm + RoPE (in place on q/k) ----------------
__global__ __launch_bounds__(256) void k_norm_rope(u16* __restrict__ qb, u16* __restrict__ kb,
    const float* __restrict__ cosp, const float* __restrict__ sinp,
    const float* __restrict__ qnw, const float* __restrict__ knw) {
  int row = blockIdx.x * 4 + (threadIdx.x >> 6);
  int lane = threadIdx.x & 63;
  const int QROWS = B_ * H_ * S_;
  u16* ptr; const float* nw; int b, s;
  if (row < QROWS) {
    ptr = qb + (size_t)row * D_; nw = qnw;
    s = row & (S_ - 1); b = row / (H_ * S_);
  } else {
    int r2 = row - QROWS;
    ptr = kb + (size_t)r2 * D_; nw = knw;
    s = r2 & (S_ - 1); b = r2 / (KVH_ * S_);
  }
  int d = lane * 2;
  float x0 = b2f(ptr[d]), x1 = b2f(ptr[d + 1]);
  float ss = x0 * x0 + x1 * x1;
#pragma unroll
  for (int m = 1; m < 64; m <<= 1) ss += __shfl_xor(ss, m);
  float inv = rsqrtf(ss * (1.0f / 128.0f) + 1e-6f);
  x0 = x0 * inv * nw[d]; x1 = x1 * inv * nw[d + 1];
  float p0 = __shfl_xor(x0, 32), p1 = __shfl_xor(x1, 32);
  float r0 = (lane < 32) ? -p0 : p0;
  float r1 = (lane < 32) ? -p1 : p1;
  const float* cp = cosp + ((size_t)b * S_ + s) * D_;
  const float* sp = sinp + ((size_t)b * S_ + s) * D_;
  ptr[d]     = f2b(x0 * cp[d]     + r0 * sp[d]);
  ptr[d + 1] = f2b(x1 * cp[d + 1] + r1 * sp[d + 1]);
}

// ---------------- causal GQA flash attention (8-warp, 32x32, swapped QK^T) -----
// grid 256 (1D, chunk-swizzled so each XCD owns one (b,kvh) -> 2MB KV in its L2).
__global__ __launch_bounds__(512, 2) void k_attn(const u16* __restrict__ q,
    const u16* __restrict__ k, const u16* __restrict__ vt, u16* __restrict__ out) {
  __shared__ u16 Kb[2 * 64 * 128];   // [kv 64][d 128], 16 slots/row, slot ^= row&15
  __shared__ u16 Vb[2 * 128 * 64];   // [d 128][kv 64],  8 slots/row, slot ^= row&7
  const int bid = blockIdx.x;
  const int wg = (bid & 7) * 32 + (bid >> 3);
  const int qx = wg & 3, bh = wg >> 2;
  const int b = bh >> 5, h = bh & 31;
  const int kvh = h >> 3;
  const int tid = threadIdx.x, lane = tid & 63, w = tid >> 6;
  const int lq = lane & 31, hi = lane >> 5;
  const u16* qp  = q  + ((size_t)(b * H_ + h) * S_) * D_;
  const u16* kp  = k  + ((size_t)(b * KVH_ + kvh) * S_) * D_;
  const u16* vtp = vt + ((size_t)(b * KVH_ + kvh) * D_) * S_;

  const int rowKa = tid >> 4;
  const int colK  = ((tid & 15) ^ (rowKa & 15)) << 3;
  const int rowVa = tid >> 3;
  const int colV  = ((tid & 7) ^ (rowVa & 7)) << 3;

  const float KSC = 0.08838834764831845f * 1.44269504088896340f;  // scale*log2e
  const f32x16 z16 = {0.f};

  int cur = 0;
  for (int half = 0; half < 2; half++) {
    const int qt = half ? (7 - qx) : qx;
    const int q0 = qt * 256;
    const int last = 4 * qt + 3;
    const int qg = q0 + 32 * w + lq;

    {
      u16* kd = Kb + cur * 8192 + tid * 8;
      u16* vd = Vb + cur * 8192 + tid * 8;
      gload_lds16(kp + (size_t)rowKa * D_ + colK, kd);
      gload_lds16(kp + (size_t)(rowKa + 32) * D_ + colK, kd + 4096);
      gload_lds16(vtp + (size_t)rowVa * S_ + colV, vd);
      gload_lds16(vtp + (size_t)(rowVa + 64) * S_ + colV, vd + 4096);
    }

    bf16x8 qf[8];
#pragma unroll
    for (int ds = 0; ds < 8; ds++)
      qf[ds] = *reinterpret_cast<const bf16x8*>(qp + (size_t)qg * D_ + ds * 16 + hi * 8);

    f32x16 oacc[4];
#pragma unroll
    for (int dt = 0; dt < 4; dt++) oacc[dt] = z16;
    float mrun = -1e30f, lrun = 0.f;

    __syncthreads();

    for (int nt = 0; nt <= last; nt++) {
      const int n0 = nt * 64;
      if (nt < last) {
        const int n1 = n0 + 64;
        u16* kd = Kb + (cur ^ 1) * 8192 + tid * 8;
        u16* vd = Vb + (cur ^ 1) * 8192 + tid * 8;
        gload_lds16(kp + (size_t)(n1 + rowKa) * D_ + colK, kd);
        gload_lds16(kp + (size_t)(n1 + rowKa + 32) * D_ + colK, kd + 4096);
        gload_lds16(vtp + (size_t)rowVa * S_ + n1 + colV, vd);
        gload_lds16(vtp + (size_t)(rowVa + 64) * S_ + n1 + colV, vd + 4096);
      }
      const u16* Kc = Kb + cur * 8192;
      const u16* Vc = Vb + cur * 8192;

      const bool skip = (n0 > q0 + 32 * w + 31);
      if (!skip) {
        const bool needmask = (n0 + 63 > q0 + 32 * w);

        f32x16 sacc[2];
        sacc[0] = z16; sacc[1] = z16;
#pragma unroll
        for (int ds = 0; ds < 8; ds++) {
          const int sl = (((ds << 1) + hi) ^ (lq & 15)) << 3;
          bf16x8 ka0 = *reinterpret_cast<const bf16x8*>(Kc + lq * 128 + sl);
          bf16x8 ka1 = *reinterpret_cast<const bf16x8*>(Kc + (lq + 32) * 128 + sl);
          __builtin_amdgcn_s_setprio(1);
          sacc[0] = __builtin_amdgcn_mfma_f32_32x32x16_bf16(ka0, qf[ds], sacc[0], 0, 0, 0);
          sacc[1] = __builtin_amdgcn_mfma_f32_32x32x16_bf16(ka1, qf[ds], sacc[1], 0, 0, 0);
          __builtin_amdgcn_s_setprio(0);
        }

        float tm = -1e30f;
#pragma unroll
        for (int t = 0; t < 2; t++)
#pragma unroll
          for (int r = 0; r < 16; r++) {
            float s2 = sacc[t][r] * KSC;
            if (needmask) {
              int kvg = n0 + 32 * t + (r & 3) + 8 * (r >> 2) + 4 * hi;
              if (kvg > qg) s2 = -1e30f;
            }
            sacc[t][r] = s2;
            tm = fmaxf(tm, s2);
          }
        tm = fmaxf(tm, __shfl_xor(tm, 32));
        if (__any(tm > mrun + 8.f)) {
          float mn = fmaxf(mrun, tm);
          float al = exp2f(mrun - mn);
          mrun = mn;
          lrun *= al;
#pragma unroll
          for (int r = 0; r < 16; r++) {
            float ar = __shfl(al, (r & 3) + 8 * (r >> 2) + 4 * hi);
#pragma unroll
            for (int dt = 0; dt < 4; dt++) oacc[dt][r] *= ar;
          }
        }
        float rs = 0.f;
#pragma unroll
        for (int t = 0; t < 2; t++)
#pragma unroll
          for (int r = 0; r < 16; r++) {
            float pv = exp2f(sacc[t][r] - mrun);
            sacc[t][r] = pv;
            rs += pv;
          }
        rs += __shfl_xor(rs, 32);
        lrun += rs;

        u32x4 pa[4];
#pragma unroll
        for (int t = 0; t < 2; t++)
#pragma unroll
          for (int ksl = 0; ksl < 2; ksl++) {
            unsigned wa, wb, wc2, wd;
            asm("v_cvt_pk_bf16_f32 %0, %1, %2" : "=v"(wa)
                : "v"(sacc[t][8 * ksl + 0]), "v"(sacc[t][8 * ksl + 1]));
            asm("v_cvt_pk_bf16_f32 %0, %1, %2" : "=v"(wb)
                : "v"(sacc[t][8 * ksl + 2]), "v"(sacc[t][8 * ksl + 3]));
            asm("v_cvt_pk_bf16_f32 %0, %1, %2" : "=v"(wc2)
                : "v"(sacc[t][8 * ksl + 4]), "v"(sacc[t][8 * ksl + 5]));
            asm("v_cvt_pk_bf16_f32 %0, %1, %2" : "=v"(wd)
                : "v"(sacc[t][8 * ksl + 6]), "v"(sacc[t][8 * ksl + 7]));
            asm("v_permlane32_swap_b32 %0, %1" : "+v"(wa), "+v"(wc2));
            asm("v_permlane32_swap_b32 %0, %1" : "+v"(wb), "+v"(wd));
            u32x4 t4 = {wa, wb, wc2, wd};
            pa[t * 2 + ksl] = t4;
          }

#pragma unroll
        for (int ks = 0; ks < 4; ks++) {
          bf16x8 paf = __builtin_bit_cast(bf16x8, pa[ks]);
          bf16x8 bv[4];
#pragma unroll
          for (int dt = 0; dt < 4; dt++) {
            int rowv = dt * 32 + lq;
            bv[dt] = *reinterpret_cast<const bf16x8*>(
                Vc + rowv * 64 + ((((ks << 1) + hi) ^ (rowv & 7)) << 3));
          }
          __builtin_amdgcn_s_setprio(1);
#pragma unroll
          for (int dt = 0; dt < 4; dt++)
            oacc[dt] = __builtin_amdgcn_mfma_f32_32x32x16_bf16(paf, bv[dt], oacc[dt], 0, 0, 0);
          __builtin_amdgcn_s_setprio(0);
        }
      }
      __syncthreads();
      cur ^= 1;
    }

    float linv = 1.0f / lrun;
#pragma unroll
    for (int r = 0; r < 16; r++) {
      const int idx_r = (r & 3) + 8 * (r >> 2) + 4 * hi;
      float lr = __shfl(linv, idx_r);
      size_t base = ((size_t)b * S_ + (q0 + 32 * w + idx_r)) * NQ_ + h * D_ + lq;
#pragma unroll
      for (int dt = 0; dt < 4; dt++)
        out[base + dt * 32] = f2b(oacc[dt][r] * lr);
    }
  }
}

extern "C" void kernel_launch(void* const* d_in, const int* in_sizes, int n_in,
                              void* d_out, int out_size, void* d_ws, size_t ws_size,
                              hipStream_t stream) {
  const float* hidden = (const float*)d_in[0];
  const float* cosp   = (const float*)d_in[1];
  const float* sinp   = (const float*)d_in[2];
  const float* q_w    = (const float*)d_in[3];
  const float* k_w    = (const float*)d_in[4];
  const float* v_w    = (const float*)d_in[5];
  const float* o_w    = (const float*)d_in[6];
  const float* qnw    = (const float*)d_in[7];
  const float* knw    = (const float*)d_in[8];

  char* p = (char*)d_ws;
  u16* hb  = (u16*)p; p += (size_t)M_ * HID_ * 2;
  u16* qwt = (u16*)p; p += (size_t)NQ_ * HID_ * 2;
  u16* kwt = (u16*)p; p += (size_t)NKV_ * HID_ * 2;
  u16* vwt = (u16*)p; p += (size_t)NKV_ * HID_ * 2;
  u16* owt = (u16*)p; p += (size_t)HID_ * NQ_ * 2;
  u16* qb  = (u16*)p; p += (size_t)B_ * H_ * S_ * D_ * 2;
  u16* kb  = (u16*)p; p += (size_t)B_ * KVH_ * S_ * D_ * 2;
  u16* vb  = (u16*)p; p += (size_t)B_ * KVH_ * S_ * D_ * 2;  // V^T [B][KVH][D][S]
  u16* ab  = (u16*)p; p += (size_t)M_ * NQ_ * 2;

  k_cvt<<<2048, 256, 0, stream>>>(hidden, hb, M_ * HID_ / 4);
  k_transpose<<<dim3(NQ_ / 64, HID_ / 64), 256, 0, stream>>>(q_w, qwt, HID_, NQ_);
  k_transpose<<<dim3(NKV_ / 64, HID_ / 64), 256, 0, stream>>>(k_w, kwt, HID_, NKV_);
  k_transpose<<<dim3(NKV_ / 64, HID_ / 64), 256, 0, stream>>>(v_w, vwt, HID_, NKV_);
  k_transpose<<<dim3(HID_ / 64, NQ_ / 64), 256, 0, stream>>>(o_w, owt, NQ_, HID_);
  k_gemm_q8<<<256, 512, 0, stream>>>(hb, qwt, qb);
  k_gemm_kv<<<256, 256, 0, stream>>>(hb, kwt, vwt, kb, vb);
  k_norm_rope<<<(B_ * H_ * S_ + B_ * KVH_ * S_) / 4, 256, 0, stream>>>(qb, kb, cosp, sinp, qnw, knw);
  k_attn<<<256, 512, 0, stream>>>(qb, kb, vb, ab);
  k_gemm_o<<<512, 256, 0, stream>>>(ab, owt, (float*)d_out);
}